// Round 6
// baseline (2074.431 us; speedup 1.0000x reference)
//
#include <hip/hip_runtime.h>
#include <hip/hip_bf16.h>
#include <stdint.h>

typedef __attribute__((ext_vector_type(8))) short bfrag;   // 8 x bf16 (4 VGPR)
typedef __attribute__((ext_vector_type(4))) float f32x4;   // MFMA acc

__device__ __forceinline__ unsigned short f2bf(float f){
  union { float f; unsigned u; } v; v.f = f;
  unsigned r = v.u + 0x7FFFu + ((v.u >> 16) & 1u);
  return (unsigned short)(r >> 16);
}
__device__ __forceinline__ f32x4 mfma16(bfrag a, bfrag b, f32x4 c){
  return __builtin_amdgcn_mfma_f32_16x16x32_bf16(a, b, c, 0, 0, 0);
}
__device__ __forceinline__ bfrag cvt8(const float* s){
  bfrag r;
  #pragma unroll
  for (int j = 0; j < 8; ++j) r[j] = (short)f2bf(s[j]);
  return r;
}

// ---------------- K0: pad + cast beats chunk (Bc,2,1020)f32 -> (Bc,2,1080)bf16 --
__global__ void k_pad(const float* __restrict__ beats, unsigned short* __restrict__ pad,
                      int NG){
  int g = blockIdx.x * 256 + threadIdx.x;
  if (g >= NG) return;
  int i8 = (g % 135) * 8;
  long rc = g / 135;                          // local b*2+c
  const float* src = beats + rc * 1020;
  union { unsigned short u[8]; bfrag s; } o;
  #pragma unroll
  for (int j = 0; j < 8; ++j){
    int i = i8 + j;
    float v = (i >= 30 && i < 1050) ? src[i - 30] : 0.f;
    o.u[j] = f2bf(v);
  }
  *(bfrag*)(pad + rc * 1080 + i8) = o.s;
}

// ---------------- K1: prep bf16 weight copies (zero-padded at ragged K) --------
__global__ void k_prep(const float* __restrict__ squ_w, const float* __restrict__ oenv_w,
                       const float* __restrict__ pose_w, const float* __restrict__ out_w,
                       const float* __restrict__ bo_w1, const float* __restrict__ bo_w2,
                       unsigned short* __restrict__ B2w, unsigned short* __restrict__ posewp,
                       unsigned short* __restrict__ B1, unsigned short* __restrict__ bow1p,
                       unsigned short* __restrict__ bow2p){
  int i = blockIdx.x * 256 + threadIdx.x;
  if (i < 24576){                                  // B2w: 128 x 192 = [squ|0|oenv|0]
    int o = i / 192, k = i - o * 192;
    float v = 0.f;
    if (k < 90) v = squ_w[o * 90 + k];
    else if (k >= 96 && k < 186) v = oenv_w[o * 90 + (k - 96)];
    B2w[i] = f2bf(v);
    return;
  }
  i -= 24576;
  if (i < 512){                                    // pose_w: 16 x 32
    int o = i / 32, k = i - o * 32;
    posewp[i] = f2bf(k < 28 ? pose_w[o * 28 + k] : 0.f);
    return;
  }
  i -= 512;
  if (i < 36864){                                  // B1: 128 x 288 = [W1|W1|Wz|0]
    int o = i / 288, k = i - o * 288;
    float v = 0.f;
    if (k < 128) v = out_w[o * 144 + k];
    else if (k < 256) v = out_w[o * 144 + (k - 128)];
    else if (k < 272) v = out_w[o * 144 + 128 + (k - 256)];
    B1[i] = f2bf(v);
    return;
  }
  i -= 36864;
  if (i < 8192){ bow1p[i] = f2bf(bo_w1[i]); return; }   // 64 x 128
  i -= 8192;
  if (i < 2048){                                   // bo_w2 padded to 32 x 64
    int o = i / 64, k = i - o * 64;
    bow2p[i] = f2bf(o < 27 ? bo_w2[o * 64 + k] : 0.f);
  }
}

// ---------------- K2: z branch (f32 math, FP32 out), full batch ----------------
__global__ void k_z(const int* __restrict__ vid, const float* __restrict__ eps,
                    const float* __restrict__ spk_table, const float* __restrict__ slw,
                    const float* __restrict__ slb, const float* __restrict__ muw,
                    const float* __restrict__ mub, const float* __restrict__ lvw,
                    const float* __restrict__ lvb,
                    float* __restrict__ outp, unsigned short* __restrict__ zws){
  int b = blockIdx.x * 256 + threadIdx.x;
  if (b >= 2048) return;
  const float* tr = spk_table + (long)vid[b] * 16;
  float t[16], zc0[16];
  #pragma unroll
  for (int k = 0; k < 16; ++k) t[k] = tr[k];
  #pragma unroll
  for (int j = 0; j < 16; ++j){
    float a = slb[j];
    #pragma unroll
    for (int k = 0; k < 16; ++k) a += t[k] * slw[j * 16 + k];
    zc0[j] = a;
  }
  const long ZC = 1880064, ZMU = 1912832, ZLV = 1945600;
  #pragma unroll
  for (int j = 0; j < 16; ++j){
    float mu = mub[j], lv = lvb[j];
    #pragma unroll
    for (int k = 0; k < 16; ++k){ mu += zc0[k] * muw[j * 16 + k]; lv += zc0[k] * lvw[j * 16 + k]; }
    float zc = mu + eps[b * 16 + j] * __expf(0.5f * lv);
    outp[ZMU + b * 16 + j] = mu;
    outp[ZLV + b * 16 + j] = lv;
    outp[ZC + b * 16 + j] = zc;
    zws[b * 16 + j] = f2bf(zc);
  }
}

// ---------------- K3: x0 = [pose | squ+oenv] chunk -> (Bc,34,160) bf16 ---------
__global__ __launch_bounds__(256) void k_x0(
    const unsigned short* __restrict__ pad, const float* __restrict__ pre_seq,
    const unsigned short* __restrict__ B2w, const unsigned short* __restrict__ posewp,
    const float* __restrict__ squ_b, const float* __restrict__ oenv_b,
    const float* __restrict__ pose_b, unsigned short* __restrict__ xbuf0){
  int bid = blockIdx.x;
  int t = bid % 34, bt = bid / 34;
  int w = threadIdx.x >> 6, lane = threadIdx.x & 63;
  int q = lane >> 4, l15 = lane & 15;
  int row = bt * 64 + w * 16 + l15;              // chunk-local row
  bfrag a[6];
  {
    const unsigned short* p0 = pad + ((long)row * 2) * 1080 + 30 * t;
    #pragma unroll
    for (int kt = 0; kt < 6; ++kt){
      int k = kt * 32 + q * 8;
      const unsigned short* src = (k < 96) ? (p0 + k) : (p0 + 1080 + (k - 96));
      const unsigned int* pu = (const unsigned int*)src;      // 4B-aligned
      union { unsigned int u[4]; bfrag s; } v;
      v.u[0] = pu[0]; v.u[1] = pu[1]; v.u[2] = pu[2]; v.u[3] = pu[3];
      a[kt] = v.s;                     // garbage past k=90/186 killed by B zeros
    }
  }
  f32x4 acc[8];
  #pragma unroll
  for (int nt = 0; nt < 8; ++nt) acc[nt] = (f32x4){0.f, 0.f, 0.f, 0.f};
  #pragma unroll
  for (int kt = 0; kt < 6; ++kt)
    #pragma unroll
    for (int nt = 0; nt < 8; ++nt){
      bfrag bf = *(const bfrag*)(B2w + ((nt * 16 + l15) * 192 + kt * 32 + q * 8));
      acc[nt] = mfma16(a[kt], bf, acc[nt]);
    }
  f32x4 accp = (f32x4){0.f, 0.f, 0.f, 0.f};
  {
    float av[8];
    const float* ps = pre_seq + ((long)row * 34 + t) * 28;
    if (q < 3){
      #pragma unroll
      for (int j = 0; j < 8; ++j) av[j] = ps[q * 8 + j];
    } else {
      #pragma unroll
      for (int j = 0; j < 4; ++j){ av[j] = ps[24 + j]; av[4 + j] = 0.f; }
    }
    bfrag ap = cvt8(av);
    bfrag bp = *(const bfrag*)(posewp + (l15 * 32 + q * 8));
    accp = mfma16(ap, bp, accp);
  }
  float pb = pose_b[l15];
  int rowc = bt * 64 + w * 16 + q * 4;
  #pragma unroll
  for (int r = 0; r < 4; ++r){
    long base = ((long)(rowc + r) * 34 + t) * 160;
    xbuf0[base + l15] = f2bf(accp[r] + pb);
    xbuf0[base + 144 + l15] = 0;
  }
  #pragma unroll
  for (int nt = 0; nt < 8; ++nt){
    int c = nt * 16 + l15;
    float sb = squ_b[c] + oenv_b[c];
    #pragma unroll
    for (int r = 0; r < 4; ++r){
      long base = ((long)(rowc + r) * 34 + t) * 160;
      xbuf0[base + 16 + c] = f2bf(acc[nt][r] + sb);
    }
  }
}

// ---------------- K4: GRU layer. 8 valid rows/block (M=16 tiles half-idle) so
// grid=2 blocks/CU -> two independent barrier groups per CU overlap each
// other's dependency/barrier stalls. Weights register-resident.
#define GRU_STEP(T, S1, S2, PR, HASP, HASGI, HASST) {                            \
    bfrag xreg = (bfrag){0,0,0,0,0,0,0,0};                                       \
    if ((HASST) && xact) xreg = *(const bfrag*)(xin_row + (long)((T)+2) * KI + xv * 8); \
    if ((HASP) && q < 2){                                                        \
      _Pragma("unroll")                                                          \
      for (int r = 0; r < 4; ++r)                                                \
        xout[((long)(rowc + r) * 34 + ((T)-1)) * 256 + d * 128 + col] = hbf[r];  \
    }                                                                            \
    f32x4 gh0 = {0,0,0,0}, gh1 = {0,0,0,0}, gh2 = {0,0,0,0};                     \
    _Pragma("unroll")                                                            \
    for (int kt = 0; kt < 4; ++kt){                                              \
      bfrag ha = *(const bfrag*)(&h_lds[PR][l15 * 136 + kt * 32 + q * 8]);       \
      gh0 = mfma16(ha, bwh[0][kt], gh0);                                         \
      gh1 = mfma16(ha, bwh[1][kt], gh1);                                         \
      gh2 = mfma16(ha, bwh[2][kt], gh2);                                         \
    }                                                                            \
    f32x4 gn0 = {0,0,0,0}, gn1 = {0,0,0,0}, gn2 = {0,0,0,0};                     \
    if (HASGI){                                                                  \
      _Pragma("unroll")                                                          \
      for (int kt = 0; kt < KIT; ++kt){                                          \
        bfrag xa = *(const bfrag*)(&x_lds[S1][l15 * (KI + 8) + kt * 32 + q * 8]);\
        gn0 = mfma16(xa, bgi[0][kt], gn0);                                       \
        gn1 = mfma16(xa, bgi[1][kt], gn1);                                       \
        gn2 = mfma16(xa, bgi[2][kt], gn2);                                       \
      }                                                                          \
    }                                                                            \
    _Pragma("unroll")                                                            \
    for (int r = 0; r < 4; ++r){                                                 \
      float ir = gc0[r] + bi0, iz = gc1[r] + bi1, inn = gc2[r] + bi2;            \
      float hr = gh0[r] + bh0, hz = gh1[r] + bh1, hn = gh2[r] + bh2;             \
      float rg = 1.f / (1.f + __expf(-(ir + hr)));                               \
      float zg = 1.f / (1.f + __expf(-(iz + hz)));                               \
      float pre = inn + rg * hn;                                                 \
      float ax = fabsf(pre);                                                     \
      float th = 1.f - 2.f / (__expf(2.f * ax) + 1.f);                           \
      th = (pre < 0.f) ? -th : th;                                               \
      float hv = (1.f - zg) * th + zg * h_old[r];                                \
      h_old[r] = hv;                                                             \
      hbf[r] = f2bf(hv);                                                         \
      h_lds[1 - (PR)][(q * 4 + r) * 136 + col] = hbf[r];                         \
    }                                                                            \
    if (HASGI){ gc0 = gn0; gc1 = gn1; gc2 = gn2; }                               \
    if ((HASST) && xact)                                                         \
      *(bfrag*)(&x_lds[S2][xrow * (KI + 8) + xv * 8]) = xreg;                    \
    __syncthreads();                                                             \
  }

template<int KIT, int KI>
__global__ __launch_bounds__(512, 4) void k_gru(
    const unsigned short* __restrict__ xin, unsigned short* __restrict__ xout,
    const float* __restrict__ wih, const float* __restrict__ whh,
    const float* __restrict__ bih, const float* __restrict__ bhh, int WK){
  __shared__ unsigned short x_lds[3][16 * (KI + 8)];   // x slots t%3 (rows 8-15 zero)
  __shared__ unsigned short h_lds[2][16 * 136];
  int d = blockIdx.x & 1, bt = blockIdx.x >> 1;        // bt: 8-row tile
  int tid = threadIdx.x;
  int w = tid >> 6, lane = tid & 63, q = lane >> 4, l15 = lane & 15;
  const float* wihd = wih + (long)d * 384 * WK;
  const float* whhd = whh + (long)d * 384 * 128;
  int col = w * 16 + l15;                        // this lane's hidden index
  float bi0 = bih[d * 384 + col], bi1 = bih[d * 384 + 128 + col], bi2 = bih[d * 384 + 256 + col];
  float bh0 = bhh[d * 384 + col], bh1 = bhh[d * 384 + 128 + col], bh2 = bhh[d * 384 + 256 + col];
  // pinned w_ih B-frags (zero-padded past WK)
  bfrag bgi[3][KIT];
  #pragma unroll
  for (int g = 0; g < 3; ++g)
    #pragma unroll
    for (int kt = 0; kt < KIT; ++kt){
      int k = kt * 32 + q * 8;
      if (k < WK){
        float tmp[8];
        const float* s = wihd + (long)(g * 128 + col) * WK + k;
        #pragma unroll
        for (int j = 0; j < 8; ++j) tmp[j] = s[j];
        bgi[g][kt] = cvt8(tmp);
      } else {
        bgi[g][kt] = (bfrag){0, 0, 0, 0, 0, 0, 0, 0};
      }
    }
  // pinned w_hh B-frags (K=128 exact)
  bfrag bwh[3][4];
  #pragma unroll
  for (int g = 0; g < 3; ++g)
    #pragma unroll
    for (int kt = 0; kt < 4; ++kt){
      float tmp[8];
      const float* s = whhd + (long)(g * 128 + col) * 128 + kt * 32 + q * 8;
      #pragma unroll
      for (int j = 0; j < 8; ++j) tmp[j] = s[j];
      bwh[g][kt] = cvt8(tmp);
    }
  const int NV = KI / 8;
  int xrow = tid / NV, xv = tid - xrow * NV;     // xrow in 0..7 for stagers
  bool xact = (tid < 8 * NV);
  const unsigned short* xin_row = xin + ((long)(bt * 8 + (xact ? xrow : 0))) * 34 * KI;
  // zero all of x_lds (rows 8-15 must be 0) and h_lds, then stage slots 0,1
  for (int i = tid; i < 3 * 16 * (KI + 8); i += 512) (&x_lds[0][0])[i] = 0;
  for (int i = tid; i < 2 * 16 * 136; i += 512) (&h_lds[0][0])[i] = 0;
  __syncthreads();
  if (xact){
    *(bfrag*)(&x_lds[0][xrow * (KI + 8) + xv * 8]) = *(const bfrag*)(xin_row + xv * 8);
    *(bfrag*)(&x_lds[1][xrow * (KI + 8) + xv * 8]) = *(const bfrag*)(xin_row + (long)KI + xv * 8);
  }
  __syncthreads();

  // prologue: gi for t=0 from slot 0
  f32x4 gc0 = {0,0,0,0}, gc1 = {0,0,0,0}, gc2 = {0,0,0,0};
  #pragma unroll
  for (int kt = 0; kt < KIT; ++kt){
    bfrag xa = *(const bfrag*)(&x_lds[0][l15 * (KI + 8) + kt * 32 + q * 8]);
    gc0 = mfma16(xa, bgi[0][kt], gc0);
    gc1 = mfma16(xa, bgi[1][kt], gc1);
    gc2 = mfma16(xa, bgi[2][kt], gc2);
  }
  f32x4 h_old = {0,0,0,0};
  unsigned short hbf[4] = {0, 0, 0, 0};
  int rowc = bt * 8 + q * 4;                     // valid global rows only for q<2

  // t: 0..5 peeled, 6..29 in a 6-step loop, 30..33 tail
  GRU_STEP(0, 1, 2, 0, false, true, true)
  GRU_STEP(1, 2, 0, 1, true,  true, true)
  GRU_STEP(2, 0, 1, 0, true,  true, true)
  GRU_STEP(3, 1, 2, 1, true,  true, true)
  GRU_STEP(4, 2, 0, 0, true,  true, true)
  GRU_STEP(5, 0, 1, 1, true,  true, true)
  for (int tt = 6; tt < 30; tt += 6){
    GRU_STEP(tt + 0, 1, 2, 0, true, true, true)
    GRU_STEP(tt + 1, 2, 0, 1, true, true, true)
    GRU_STEP(tt + 2, 0, 1, 0, true, true, true)
    GRU_STEP(tt + 3, 1, 2, 1, true, true, true)
    GRU_STEP(tt + 4, 2, 0, 0, true, true, true)
    GRU_STEP(tt + 5, 0, 1, 1, true, true, true)
  }
  GRU_STEP(30, 1, 2, 0, true, true, true)
  GRU_STEP(31, 2, 0, 1, true, true, true)
  GRU_STEP(32, 0, 1, 0, true, true, false)
  GRU_STEP(33, 1, 2, 1, true, false, false)
  if (q < 2){
    #pragma unroll
    for (int r = 0; r < 4; ++r)
      xout[((long)(rowc + r) * 34 + 33) * 256 + d * 128 + col] = hbf[r];
  }
}

// ---------------- K5: head chunk — feat -> bo1 -> bo2 -> beat (FP32 out) -------
__global__ __launch_bounds__(512) void k_head(
    const unsigned short* __restrict__ xb, const unsigned short* __restrict__ zloc,
    const unsigned short* __restrict__ B1p, const unsigned short* __restrict__ bow1p,
    const unsigned short* __restrict__ bow2p,
    const float* __restrict__ out_b, const float* __restrict__ bo_b1,
    const float* __restrict__ bo_b2, float* __restrict__ outp){
  __shared__ unsigned short B1_lds[128 * 296];
  __shared__ unsigned short feat_lds[128 * 136];
  __shared__ unsigned short bt1_lds[128 * 72];
  int tid = threadIdx.x, w = tid >> 6, lane = tid & 63, q = lane >> 4, l15 = lane & 15;
  long rbase = (long)blockIdx.x * 128;              // chunk-local flattened (b,t)
  for (int v = tid; v < 128 * 36; v += 512){
    int n = v / 36, kc = (v - n * 36) * 8;
    *(bfrag*)(&B1_lds[n * 296 + kc]) = *(const bfrag*)(B1p + n * 288 + kc);
  }
  __syncthreads();
  int rloc = w * 16 + l15;
  long rt = rbase + rloc;
  int bidx = (int)(rt / 34);                        // chunk-local batch
  bfrag a1[9];
  #pragma unroll
  for (int kt = 0; kt < 8; ++kt)
    a1[kt] = *(const bfrag*)(xb + rt * 256 + kt * 32 + q * 8);
  if (q < 2) a1[8] = *(const bfrag*)(zloc + (long)bidx * 16 + q * 8);
  else       a1[8] = (bfrag){0, 0, 0, 0, 0, 0, 0, 0};
  f32x4 acc[8];
  #pragma unroll
  for (int nt = 0; nt < 8; ++nt) acc[nt] = (f32x4){0.f, 0.f, 0.f, 0.f};
  #pragma unroll
  for (int kt = 0; kt < 9; ++kt)
    #pragma unroll
    for (int nt = 0; nt < 8; ++nt){
      bfrag b = *(const bfrag*)(&B1_lds[(nt * 16 + l15) * 296 + kt * 32 + q * 8]);
      acc[nt] = mfma16(a1[kt], b, acc[nt]);
    }
  #pragma unroll
  for (int nt = 0; nt < 8; ++nt){
    float bb = out_b[nt * 16 + l15];
    #pragma unroll
    for (int r = 0; r < 4; ++r)
      feat_lds[(w * 16 + q * 4 + r) * 136 + nt * 16 + l15] = f2bf(acc[nt][r] + bb);
  }
  __syncthreads();
  bfrag a2[4];
  #pragma unroll
  for (int kt = 0; kt < 4; ++kt)
    a2[kt] = *(const bfrag*)(&feat_lds[rloc * 136 + kt * 32 + q * 8]);
  f32x4 acc2[4];
  #pragma unroll
  for (int nt = 0; nt < 4; ++nt) acc2[nt] = (f32x4){0.f, 0.f, 0.f, 0.f};
  #pragma unroll
  for (int kt = 0; kt < 4; ++kt)
    #pragma unroll
    for (int nt = 0; nt < 4; ++nt){
      bfrag b = *(const bfrag*)(bow1p + ((nt * 16 + l15) * 128 + kt * 32 + q * 8));
      acc2[nt] = mfma16(a2[kt], b, acc2[nt]);
    }
  #pragma unroll
  for (int nt = 0; nt < 4; ++nt){
    float bb = bo_b1[nt * 16 + l15];
    #pragma unroll
    for (int r = 0; r < 4; ++r)
      bt1_lds[(w * 16 + q * 4 + r) * 72 + nt * 16 + l15] = f2bf(acc2[nt][r] + bb);
  }
  __syncthreads();
  bfrag a3[2];
  #pragma unroll
  for (int kt = 0; kt < 2; ++kt)
    a3[kt] = *(const bfrag*)(&bt1_lds[rloc * 72 + kt * 32 + q * 8]);
  f32x4 acc3[2];
  #pragma unroll
  for (int nt = 0; nt < 2; ++nt) acc3[nt] = (f32x4){0.f, 0.f, 0.f, 0.f};
  #pragma unroll
  for (int kt = 0; kt < 2; ++kt)
    #pragma unroll
    for (int nt = 0; nt < 2; ++nt){
      bfrag b = *(const bfrag*)(bow2p + ((nt * 16 + l15) * 64 + kt * 32 + q * 8));
      acc3[nt] = mfma16(a3[kt], b, acc3[nt]);
    }
  #pragma unroll
  for (int nt = 0; nt < 2; ++nt){
    int n = nt * 16 + l15;
    if (n < 27){
      float bb = bo_b2[n];
      #pragma unroll
      for (int r = 0; r < 4; ++r){
        long rowg = rbase + w * 16 + q * 4 + r;
        outp[rowg * 27 + n] = acc3[nt][r] + bb;
      }
    }
  }
}

extern "C" void kernel_launch(void* const* d_in, const int* in_sizes, int n_in,
                              void* d_out, int out_size, void* d_ws, size_t ws_size,
                              hipStream_t stream){
  (void)in_sizes; (void)n_in; (void)out_size;
  const float* pre_seq = (const float*)d_in[0];
  const float* beats   = (const float*)d_in[1];
  const int*   vid     = (const int*)d_in[4];
  const float* eps     = (const float*)d_in[5];
  const float* spk_table = (const float*)d_in[6];
  const float* slw = (const float*)d_in[7];
  const float* slb = (const float*)d_in[8];
  const float* muw = (const float*)d_in[9];
  const float* mub = (const float*)d_in[10];
  const float* lvw = (const float*)d_in[11];
  const float* lvb = (const float*)d_in[12];
  const float* squ_w = (const float*)d_in[13];
  const float* squ_b = (const float*)d_in[14];
  const float* oenv_w = (const float*)d_in[15];
  const float* oenv_b = (const float*)d_in[16];
  const float* pose_w = (const float*)d_in[17];
  const float* pose_b = (const float*)d_in[18];
  const float* out_w = (const float*)d_in[19];
  const float* out_b = (const float*)d_in[20];
  const float* bo_w1 = (const float*)d_in[21];
  const float* bo_b1 = (const float*)d_in[22];
  const float* bo_w2 = (const float*)d_in[23];
  const float* bo_b2 = (const float*)d_in[24];
  const float* w_ih_l0 = (const float*)d_in[25];
  const float* w_hh_l0 = (const float*)d_in[26];
  const float* b_ih_l0 = (const float*)d_in[27];
  const float* b_hh_l0 = (const float*)d_in[28];
  const float* w_ih = (const float*)d_in[29];
  const float* w_hh = (const float*)d_in[30];
  const float* b_ih = (const float*)d_in[31];
  const float* b_hh = (const float*)d_in[32];
  float* outp = (float*)d_out;                     // FP32 output (verified r3)
  unsigned short* ws = (unsigned short*)d_ws;

  // Small buffers at ws front.
  const long o_z     = 0;                        // (2048,16) bf16 for head
  const long o_B2w   = 32768;                    // 128x192
  const long o_posew = o_B2w + 24576;            // 16x32
  const long o_B1    = o_posew + 512;            // 128x288
  const long o_bw1   = o_B1 + 36864;             // 64x128
  const long o_bw2   = o_bw1 + 8192;             // 32x64
  const long o_chunk = o_bw2 + 2048;             // = 104960 elements

  // Footprint-adaptive chunking: per-row cost = pad 2160 + x0 5440 + A 8704 + B 8704
  int Bc;
  {
    const size_t margin = 1u << 20;
    size_t need2048 = (size_t)(o_chunk + 2048L * 25008) * 2 + margin;
    size_t need512  = (size_t)(o_chunk + 512L  * 25008) * 2 + margin;
    if      (ws_size >= need2048) Bc = 2048;
    else if (ws_size >= need512)  Bc = 512;
    else                          Bc = 128;
  }
  const int C = 2048 / Bc;
  const long o_pad = o_chunk;
  const long o_x0  = o_pad + (long)Bc * 2160;
  const long o_A   = o_x0  + (long)Bc * 5440;
  const long o_B   = o_A   + (long)Bc * 8704;

  k_prep<<<282, 256, 0, stream>>>(squ_w, oenv_w, pose_w, out_w, bo_w1, bo_w2,
                                  ws + o_B2w, ws + o_posew, ws + o_B1, ws + o_bw1, ws + o_bw2);
  k_z<<<8, 256, 0, stream>>>(vid, eps, spk_table, slw, slb, muw, mub, lvw, lvb, outp, ws + o_z);

  for (int c = 0; c < C; ++c){
    long b0 = (long)c * Bc;
    int NG = Bc * 270;                           // Bc*2*135
    k_pad<<<NG / 256, 256, 0, stream>>>(beats + b0 * 2040, ws + o_pad, NG);
    k_x0<<<34 * (Bc / 64), 256, 0, stream>>>(ws + o_pad, pre_seq + b0 * 952,
                                             ws + o_B2w, ws + o_posew,
                                             squ_b, oenv_b, pose_b, ws + o_x0);
    k_gru<5, 160><<<Bc / 4, 512, 0, stream>>>(ws + o_x0, ws + o_A,
                                              w_ih_l0, w_hh_l0, b_ih_l0, b_hh_l0, 144);
    k_gru<8, 256><<<Bc / 4, 512, 0, stream>>>(ws + o_A, ws + o_B,
                                              w_ih, w_hh, b_ih, b_hh, 256);
    k_gru<8, 256><<<Bc / 4, 512, 0, stream>>>(ws + o_B, ws + o_A,
                                              w_ih + 1L * 2 * 384 * 256, w_hh + 1L * 2 * 384 * 128,
                                              b_ih + 2 * 384, b_hh + 2 * 384, 256);
    k_gru<8, 256><<<Bc / 4, 512, 0, stream>>>(ws + o_A, ws + o_B,
                                              w_ih + 2L * 2 * 384 * 256, w_hh + 2L * 2 * 384 * 128,
                                              b_ih + 4 * 384, b_hh + 4 * 384, 256);
    k_head<<<Bc * 34 / 128, 512, 0, stream>>>(ws + o_B, ws + o_z,
                                              ws + o_B1, ws + o_bw1, ws + o_bw2,
                                              out_b, bo_b1, bo_b2, outp + b0 * 918);
  }
}

// Round 7
// 763.651 us; speedup vs baseline: 2.7165x; 2.7165x over previous
//
#include <hip/hip_runtime.h>
#include <hip/hip_bf16.h>
#include <stdint.h>

typedef __attribute__((ext_vector_type(8))) short bfrag;   // 8 x bf16 (4 VGPR)
typedef __attribute__((ext_vector_type(4))) short bf4;     // 4 x bf16 (2 VGPR)
typedef __attribute__((ext_vector_type(4))) float f32x4;   // MFMA acc

__device__ __forceinline__ unsigned short f2bf(float f){
  union { float f; unsigned u; } v; v.f = f;
  unsigned r = v.u + 0x7FFFu + ((v.u >> 16) & 1u);
  return (unsigned short)(r >> 16);
}
__device__ __forceinline__ float bf2f(unsigned short u){
  union { unsigned u; float f; } v; v.u = ((unsigned)u) << 16; return v.f;
}
__device__ __forceinline__ f32x4 mfma16(bfrag a, bfrag b, f32x4 c){
  return __builtin_amdgcn_mfma_f32_16x16x32_bf16(a, b, c, 0, 0, 0);
}
__device__ __forceinline__ bfrag cvt8(const float* s){
  bfrag r;
  #pragma unroll
  for (int j = 0; j < 8; ++j) r[j] = (short)f2bf(s[j]);
  return r;
}

// ---------------- K0: pad + cast beats chunk (Bc,2,1020)f32 -> (Bc,2,1080)bf16 --
__global__ void k_pad(const float* __restrict__ beats, unsigned short* __restrict__ pad,
                      int NG){
  int g = blockIdx.x * 256 + threadIdx.x;
  if (g >= NG) return;
  int i8 = (g % 135) * 8;
  long rc = g / 135;
  const float* src = beats + rc * 1020;
  union { unsigned short u[8]; bfrag s; } o;
  #pragma unroll
  for (int j = 0; j < 8; ++j){
    int i = i8 + j;
    float v = (i >= 30 && i < 1050) ? src[i - 30] : 0.f;
    o.u[j] = f2bf(v);
  }
  *(bfrag*)(pad + rc * 1080 + i8) = o.s;
}

// ---------------- K1: prep bf16 weight copies (zero-padded at ragged K) --------
__global__ void k_prep(const float* __restrict__ squ_w, const float* __restrict__ oenv_w,
                       const float* __restrict__ pose_w, const float* __restrict__ out_w,
                       const float* __restrict__ bo_w1, const float* __restrict__ bo_w2,
                       unsigned short* __restrict__ B2w, unsigned short* __restrict__ posewp,
                       unsigned short* __restrict__ B1, unsigned short* __restrict__ bow1p,
                       unsigned short* __restrict__ bow2p){
  int i = blockIdx.x * 256 + threadIdx.x;
  if (i < 24576){                                  // B2w: 128 x 192 = [squ|0|oenv|0]
    int o = i / 192, k = i - o * 192;
    float v = 0.f;
    if (k < 90) v = squ_w[o * 90 + k];
    else if (k >= 96 && k < 186) v = oenv_w[o * 90 + (k - 96)];
    B2w[i] = f2bf(v);
    return;
  }
  i -= 24576;
  if (i < 512){                                    // pose_w: 16 x 32
    int o = i / 32, k = i - o * 32;
    posewp[i] = f2bf(k < 28 ? pose_w[o * 28 + k] : 0.f);
    return;
  }
  i -= 512;
  if (i < 36864){                                  // B1: 128 x 288 = [W1|W1|Wz|0]
    int o = i / 288, k = i - o * 288;
    float v = 0.f;
    if (k < 128) v = out_w[o * 144 + k];
    else if (k < 256) v = out_w[o * 144 + (k - 128)];
    else if (k < 272) v = out_w[o * 144 + 128 + (k - 256)];
    B1[i] = f2bf(v);
    return;
  }
  i -= 36864;
  if (i < 8192){ bow1p[i] = f2bf(bo_w1[i]); return; }   // 64 x 128
  i -= 8192;
  if (i < 2048){                                   // bo_w2 padded to 32 x 64
    int o = i / 64, k = i - o * 64;
    bow2p[i] = f2bf(o < 27 ? bo_w2[o * 64 + k] : 0.f);
  }
}

// ---------------- K2: z branch (f32 math, FP32 out), full batch ----------------
__global__ void k_z(const int* __restrict__ vid, const float* __restrict__ eps,
                    const float* __restrict__ spk_table, const float* __restrict__ slw,
                    const float* __restrict__ slb, const float* __restrict__ muw,
                    const float* __restrict__ mub, const float* __restrict__ lvw,
                    const float* __restrict__ lvb,
                    float* __restrict__ outp, unsigned short* __restrict__ zws){
  int b = blockIdx.x * 256 + threadIdx.x;
  if (b >= 2048) return;
  const float* tr = spk_table + (long)vid[b] * 16;
  float t[16], zc0[16];
  #pragma unroll
  for (int k = 0; k < 16; ++k) t[k] = tr[k];
  #pragma unroll
  for (int j = 0; j < 16; ++j){
    float a = slb[j];
    #pragma unroll
    for (int k = 0; k < 16; ++k) a += t[k] * slw[j * 16 + k];
    zc0[j] = a;
  }
  const long ZC = 1880064, ZMU = 1912832, ZLV = 1945600;
  #pragma unroll
  for (int j = 0; j < 16; ++j){
    float mu = mub[j], lv = lvb[j];
    #pragma unroll
    for (int k = 0; k < 16; ++k){ mu += zc0[k] * muw[j * 16 + k]; lv += zc0[k] * lvw[j * 16 + k]; }
    float zc = mu + eps[b * 16 + j] * __expf(0.5f * lv);
    outp[ZMU + b * 16 + j] = mu;
    outp[ZLV + b * 16 + j] = lv;
    outp[ZC + b * 16 + j] = zc;
    zws[b * 16 + j] = f2bf(zc);
  }
}

// ---------------- K3: x0 = [pose | squ+oenv] chunk -> (Bc,34,160) bf16 ---------
__global__ __launch_bounds__(256) void k_x0(
    const unsigned short* __restrict__ pad, const float* __restrict__ pre_seq,
    const unsigned short* __restrict__ B2w, const unsigned short* __restrict__ posewp,
    const float* __restrict__ squ_b, const float* __restrict__ oenv_b,
    const float* __restrict__ pose_b, unsigned short* __restrict__ xbuf0){
  int bid = blockIdx.x;
  int t = bid % 34, bt = bid / 34;
  int w = threadIdx.x >> 6, lane = threadIdx.x & 63;
  int q = lane >> 4, l15 = lane & 15;
  int row = bt * 64 + w * 16 + l15;
  bfrag a[6];
  {
    const unsigned short* p0 = pad + ((long)row * 2) * 1080 + 30 * t;
    #pragma unroll
    for (int kt = 0; kt < 6; ++kt){
      int k = kt * 32 + q * 8;
      const unsigned short* src = (k < 96) ? (p0 + k) : (p0 + 1080 + (k - 96));
      const unsigned int* pu = (const unsigned int*)src;
      union { unsigned int u[4]; bfrag s; } v;
      v.u[0] = pu[0]; v.u[1] = pu[1]; v.u[2] = pu[2]; v.u[3] = pu[3];
      a[kt] = v.s;
    }
  }
  f32x4 acc[8];
  #pragma unroll
  for (int nt = 0; nt < 8; ++nt) acc[nt] = (f32x4){0.f, 0.f, 0.f, 0.f};
  #pragma unroll
  for (int kt = 0; kt < 6; ++kt)
    #pragma unroll
    for (int nt = 0; nt < 8; ++nt){
      bfrag bf = *(const bfrag*)(B2w + ((nt * 16 + l15) * 192 + kt * 32 + q * 8));
      acc[nt] = mfma16(a[kt], bf, acc[nt]);
    }
  f32x4 accp = (f32x4){0.f, 0.f, 0.f, 0.f};
  {
    float av[8];
    const float* ps = pre_seq + ((long)row * 34 + t) * 28;
    if (q < 3){
      #pragma unroll
      for (int j = 0; j < 8; ++j) av[j] = ps[q * 8 + j];
    } else {
      #pragma unroll
      for (int j = 0; j < 4; ++j){ av[j] = ps[24 + j]; av[4 + j] = 0.f; }
    }
    bfrag ap = cvt8(av);
    bfrag bp = *(const bfrag*)(posewp + (l15 * 32 + q * 8));
    accp = mfma16(ap, bp, accp);
  }
  float pb = pose_b[l15];
  int rowc = bt * 64 + w * 16 + q * 4;
  #pragma unroll
  for (int r = 0; r < 4; ++r){
    long base = ((long)(rowc + r) * 34 + t) * 160;
    xbuf0[base + l15] = f2bf(accp[r] + pb);
    xbuf0[base + 144 + l15] = 0;
  }
  #pragma unroll
  for (int nt = 0; nt < 8; ++nt){
    int c = nt * 16 + l15;
    float sb = squ_b[c] + oenv_b[c];
    #pragma unroll
    for (int r = 0; r < 4; ++r){
      long base = ((long)(rowc + r) * 34 + t) * 160;
      xbuf0[base + 16 + c] = f2bf(acc[nt][r] + sb);
    }
  }
}

// ---------------- K4a: GI = x @ wih^T + bih, all t (no recurrence) -------------
// Block: 16 rows x 1 dir, 8 waves; wave w owns col slice w*16+l15 for all 3 gates.
// GI layout: [bt16][d][t][g][col(128)][row16] bf16 -> 512B-coalesced stores/loads.
template<int KIT, int KI>
__global__ __launch_bounds__(512, 2) void k_gi(
    const unsigned short* __restrict__ xin, unsigned short* __restrict__ gi,
    const float* __restrict__ wih, const float* __restrict__ bih, int WK){
  __shared__ unsigned short x_lds[3][16 * (KI + 8)];
  int d = blockIdx.x & 1, bt = blockIdx.x >> 1;
  int tid = threadIdx.x;
  int w = tid >> 6, lane = tid & 63, q = lane >> 4, l15 = lane & 15;
  const float* wihd = wih + (long)d * 384 * WK;
  int col = w * 16 + l15;
  float bib0 = bih[d * 384 + col], bib1 = bih[d * 384 + 128 + col], bib2 = bih[d * 384 + 256 + col];
  bfrag bgi[3][KIT];
  #pragma unroll
  for (int g = 0; g < 3; ++g)
    #pragma unroll
    for (int kt = 0; kt < KIT; ++kt){
      int k = kt * 32 + q * 8;
      if (k < WK){
        float tmp[8];
        const float* s = wihd + (long)(g * 128 + col) * WK + k;
        #pragma unroll
        for (int j = 0; j < 8; ++j) tmp[j] = s[j];
        bgi[g][kt] = cvt8(tmp);
      } else {
        bgi[g][kt] = (bfrag){0, 0, 0, 0, 0, 0, 0, 0};
      }
    }
  const int NV = KI / 8;
  int xrow = tid / NV, xv = tid - xrow * NV;
  bool xact = (tid < 16 * NV);
  const unsigned short* xin_row = xin + ((long)(bt * 16 + (xact ? xrow : 0))) * 34 * KI;
  if (xact){
    *(bfrag*)(&x_lds[0][xrow * (KI + 8) + xv * 8]) = *(const bfrag*)(xin_row + xv * 8);
    *(bfrag*)(&x_lds[1][xrow * (KI + 8) + xv * 8]) = *(const bfrag*)(xin_row + (long)KI + xv * 8);
  }
  __syncthreads();
  long gib = (long)(bt * 2 + d) * 34 * 3 * 2048;   // 2048 = 128 cols * 16 rows
  int s0 = 0, s1 = 1, s2 = 2;
  for (int t = 0; t < 34; ++t){
    bfrag xpf = (bfrag){0, 0, 0, 0, 0, 0, 0, 0};
    if (xact && t + 2 < 34)
      xpf = *(const bfrag*)(xin_row + (long)(t + 2) * KI + xv * 8);
    f32x4 a0 = {0,0,0,0}, a1 = {0,0,0,0}, a2 = {0,0,0,0};
    #pragma unroll
    for (int kt = 0; kt < KIT; ++kt){
      bfrag xa = *(const bfrag*)(&x_lds[s0][l15 * (KI + 8) + kt * 32 + q * 8]);
      a0 = mfma16(xa, bgi[0][kt], a0);
      a1 = mfma16(xa, bgi[1][kt], a1);
      a2 = mfma16(xa, bgi[2][kt], a2);
    }
    long tb = gib + (long)t * 3 * 2048;
    bf4 v0, v1, v2;
    #pragma unroll
    for (int r = 0; r < 4; ++r){
      v0[r] = (short)f2bf(a0[r] + bib0);
      v1[r] = (short)f2bf(a1[r] + bib1);
      v2[r] = (short)f2bf(a2[r] + bib2);
    }
    *(bf4*)(gi + tb + 0 * 2048 + col * 16 + q * 4) = v0;
    *(bf4*)(gi + tb + 1 * 2048 + col * 16 + q * 4) = v1;
    *(bf4*)(gi + tb + 2 * 2048 + col * 16 + q * 4) = v2;
    if (xact && t + 2 < 34)
      *(bfrag*)(&x_lds[s2][xrow * (KI + 8) + xv * 8]) = xpf;
    int tmp = s0; s0 = s1; s1 = s2; s2 = tmp;
    __syncthreads();
  }
}

// ---------------- K4b: recurrence only. Block = 4 waves, 8 valid rows, 1 dir. --
// whh register-resident (wave w owns cols w*32..w*32+31); h via LDS; GI from
// global (coalesced, prefetched 1 step). 512 blocks -> 2 barrier groups / CU.
__global__ __launch_bounds__(256, 2) void k_rec(
    const unsigned short* __restrict__ gi, unsigned short* __restrict__ xout,
    const float* __restrict__ whh, const float* __restrict__ bhh){
  __shared__ unsigned short h_lds[2][16 * 136];
  int d = blockIdx.x & 1, g8 = blockIdx.x >> 1;    // g8: 8-row group
  int bt16 = g8 >> 1, r16b = (g8 & 1) * 8;
  int tid = threadIdx.x;
  int w = tid >> 6, lane = tid & 63, q = lane >> 4, l15 = lane & 15;
  const float* whhd = whh + (long)d * 384 * 128;
  int c0 = w * 32 + l15, c1 = w * 32 + 16 + l15;   // this lane's two hidden cols
  bfrag bwh[3][2][4];
  #pragma unroll
  for (int g = 0; g < 3; ++g)
    #pragma unroll
    for (int tl = 0; tl < 2; ++tl)
      #pragma unroll
      for (int kt = 0; kt < 4; ++kt){
        float tmp[8];
        const float* s = whhd + (long)(g * 128 + (tl ? c1 : c0)) * 128 + kt * 32 + q * 8;
        #pragma unroll
        for (int j = 0; j < 8; ++j) tmp[j] = s[j];
        bwh[g][tl][kt] = cvt8(tmp);
      }
  float bh[3][2];
  #pragma unroll
  for (int g = 0; g < 3; ++g){
    bh[g][0] = bhh[d * 384 + g * 128 + c0];
    bh[g][1] = bhh[d * 384 + g * 128 + c1];
  }
  for (int i = tid; i < 2 * 16 * 136; i += 256) (&h_lds[0][0])[i] = 0;
  __syncthreads();
  int rq = (q < 2) ? q * 4 : 0;
  long gib = (long)(bt16 * 2 + d) * 34 * 3 * 2048;
  bf4 cur[3][2], nxt[3][2];
  #pragma unroll
  for (int g = 0; g < 3; ++g){
    cur[g][0] = *(const bf4*)(gi + gib + (long)g * 2048 + c0 * 16 + r16b + rq);
    cur[g][1] = *(const bf4*)(gi + gib + (long)g * 2048 + c1 * 16 + r16b + rq);
  }
  f32x4 ho[2] = {{0,0,0,0},{0,0,0,0}};
  int p = 0;
  int rowc = g8 * 8 + q * 4;
  for (int t = 0; t < 34; ++t){
    if (t + 1 < 34){
      long tb = gib + (long)(t + 1) * 3 * 2048;
      #pragma unroll
      for (int g = 0; g < 3; ++g){
        nxt[g][0] = *(const bf4*)(gi + tb + (long)g * 2048 + c0 * 16 + r16b + rq);
        nxt[g][1] = *(const bf4*)(gi + tb + (long)g * 2048 + c1 * 16 + r16b + rq);
      }
    }
    bfrag ha[4];
    #pragma unroll
    for (int kt = 0; kt < 4; ++kt)
      ha[kt] = *(const bfrag*)(&h_lds[p][l15 * 136 + kt * 32 + q * 8]);
    f32x4 gh[3][2];
    #pragma unroll
    for (int g = 0; g < 3; ++g){ gh[g][0] = (f32x4){0,0,0,0}; gh[g][1] = (f32x4){0,0,0,0}; }
    #pragma unroll
    for (int kt = 0; kt < 4; ++kt)
      #pragma unroll
      for (int g = 0; g < 3; ++g){
        gh[g][0] = mfma16(ha[kt], bwh[g][0][kt], gh[g][0]);
        gh[g][1] = mfma16(ha[kt], bwh[g][1][kt], gh[g][1]);
      }
    #pragma unroll
    for (int tl = 0; tl < 2; ++tl){
      int cc = tl ? c1 : c0;
      #pragma unroll
      for (int r = 0; r < 4; ++r){
        float ir  = bf2f((unsigned short)cur[0][tl][r]);
        float iz  = bf2f((unsigned short)cur[1][tl][r]);
        float inn = bf2f((unsigned short)cur[2][tl][r]);
        float hr = gh[0][tl][r] + bh[0][tl];
        float hz = gh[1][tl][r] + bh[1][tl];
        float hn = gh[2][tl][r] + bh[2][tl];
        float rg = 1.f / (1.f + __expf(-(ir + hr)));
        float zg = 1.f / (1.f + __expf(-(iz + hz)));
        float pre = inn + rg * hn;
        float ax = fabsf(pre);
        float th = 1.f - 2.f / (__expf(2.f * ax) + 1.f);
        th = (pre < 0.f) ? -th : th;
        float hv = (1.f - zg) * th + zg * ho[tl][r];
        ho[tl][r] = hv;
        unsigned short hb = f2bf(hv);
        h_lds[1 - p][(q * 4 + r) * 136 + cc] = hb;
        if (q < 2)
          xout[((long)(rowc + r) * 34 + t) * 256 + d * 128 + cc] = hb;
      }
    }
    #pragma unroll
    for (int g = 0; g < 3; ++g){ cur[g][0] = nxt[g][0]; cur[g][1] = nxt[g][1]; }
    p ^= 1;
    __syncthreads();
  }
}

// ---------------- K5: head chunk — feat -> bo1 -> bo2 -> beat (FP32 out) -------
__global__ __launch_bounds__(512) void k_head(
    const unsigned short* __restrict__ xb, const unsigned short* __restrict__ zloc,
    const unsigned short* __restrict__ B1p, const unsigned short* __restrict__ bow1p,
    const unsigned short* __restrict__ bow2p,
    const float* __restrict__ out_b, const float* __restrict__ bo_b1,
    const float* __restrict__ bo_b2, float* __restrict__ outp){
  __shared__ unsigned short B1_lds[128 * 296];
  __shared__ unsigned short feat_lds[128 * 136];
  __shared__ unsigned short bt1_lds[128 * 72];
  int tid = threadIdx.x, w = tid >> 6, lane = tid & 63, q = lane >> 4, l15 = lane & 15;
  long rbase = (long)blockIdx.x * 128;
  for (int v = tid; v < 128 * 36; v += 512){
    int n = v / 36, kc = (v - n * 36) * 8;
    *(bfrag*)(&B1_lds[n * 296 + kc]) = *(const bfrag*)(B1p + n * 288 + kc);
  }
  __syncthreads();
  int rloc = w * 16 + l15;
  long rt = rbase + rloc;
  int bidx = (int)(rt / 34);
  bfrag a1[9];
  #pragma unroll
  for (int kt = 0; kt < 8; ++kt)
    a1[kt] = *(const bfrag*)(xb + rt * 256 + kt * 32 + q * 8);
  if (q < 2) a1[8] = *(const bfrag*)(zloc + (long)bidx * 16 + q * 8);
  else       a1[8] = (bfrag){0, 0, 0, 0, 0, 0, 0, 0};
  f32x4 acc[8];
  #pragma unroll
  for (int nt = 0; nt < 8; ++nt) acc[nt] = (f32x4){0.f, 0.f, 0.f, 0.f};
  #pragma unroll
  for (int kt = 0; kt < 9; ++kt)
    #pragma unroll
    for (int nt = 0; nt < 8; ++nt){
      bfrag b = *(const bfrag*)(&B1_lds[(nt * 16 + l15) * 296 + kt * 32 + q * 8]);
      acc[nt] = mfma16(a1[kt], b, acc[nt]);
    }
  #pragma unroll
  for (int nt = 0; nt < 8; ++nt){
    float bb = out_b[nt * 16 + l15];
    #pragma unroll
    for (int r = 0; r < 4; ++r)
      feat_lds[(w * 16 + q * 4 + r) * 136 + nt * 16 + l15] = f2bf(acc[nt][r] + bb);
  }
  __syncthreads();
  bfrag a2[4];
  #pragma unroll
  for (int kt = 0; kt < 4; ++kt)
    a2[kt] = *(const bfrag*)(&feat_lds[rloc * 136 + kt * 32 + q * 8]);
  f32x4 acc2[4];
  #pragma unroll
  for (int nt = 0; nt < 4; ++nt) acc2[nt] = (f32x4){0.f, 0.f, 0.f, 0.f};
  #pragma unroll
  for (int kt = 0; kt < 4; ++kt)
    #pragma unroll
    for (int nt = 0; nt < 4; ++nt){
      bfrag b = *(const bfrag*)(bow1p + ((nt * 16 + l15) * 128 + kt * 32 + q * 8));
      acc2[nt] = mfma16(a2[kt], b, acc2[nt]);
    }
  #pragma unroll
  for (int nt = 0; nt < 4; ++nt){
    float bb = bo_b1[nt * 16 + l15];
    #pragma unroll
    for (int r = 0; r < 4; ++r)
      bt1_lds[(w * 16 + q * 4 + r) * 72 + nt * 16 + l15] = f2bf(acc2[nt][r] + bb);
  }
  __syncthreads();
  bfrag a3[2];
  #pragma unroll
  for (int kt = 0; kt < 2; ++kt)
    a3[kt] = *(const bfrag*)(&bt1_lds[rloc * 72 + kt * 32 + q * 8]);
  f32x4 acc3[2];
  #pragma unroll
  for (int nt = 0; nt < 2; ++nt) acc3[nt] = (f32x4){0.f, 0.f, 0.f, 0.f};
  #pragma unroll
  for (int kt = 0; kt < 2; ++kt)
    #pragma unroll
    for (int nt = 0; nt < 2; ++nt){
      bfrag b = *(const bfrag*)(bow2p + ((nt * 16 + l15) * 64 + kt * 32 + q * 8));
      acc3[nt] = mfma16(a3[kt], b, acc3[nt]);
    }
  #pragma unroll
  for (int nt = 0; nt < 2; ++nt){
    int n = nt * 16 + l15;
    if (n < 27){
      float bb = bo_b2[n];
      #pragma unroll
      for (int r = 0; r < 4; ++r){
        long rowg = rbase + w * 16 + q * 4 + r;
        outp[rowg * 27 + n] = acc3[nt][r] + bb;
      }
    }
  }
}

extern "C" void kernel_launch(void* const* d_in, const int* in_sizes, int n_in,
                              void* d_out, int out_size, void* d_ws, size_t ws_size,
                              hipStream_t stream){
  (void)in_sizes; (void)n_in; (void)out_size;
  const float* pre_seq = (const float*)d_in[0];
  const float* beats   = (const float*)d_in[1];
  const int*   vid     = (const int*)d_in[4];
  const float* eps     = (const float*)d_in[5];
  const float* spk_table = (const float*)d_in[6];
  const float* slw = (const float*)d_in[7];
  const float* slb = (const float*)d_in[8];
  const float* muw = (const float*)d_in[9];
  const float* mub = (const float*)d_in[10];
  const float* lvw = (const float*)d_in[11];
  const float* lvb = (const float*)d_in[12];
  const float* squ_w = (const float*)d_in[13];
  const float* squ_b = (const float*)d_in[14];
  const float* oenv_w = (const float*)d_in[15];
  const float* oenv_b = (const float*)d_in[16];
  const float* pose_w = (const float*)d_in[17];
  const float* pose_b = (const float*)d_in[18];
  const float* out_w = (const float*)d_in[19];
  const float* out_b = (const float*)d_in[20];
  const float* bo_w1 = (const float*)d_in[21];
  const float* bo_b1 = (const float*)d_in[22];
  const float* bo_w2 = (const float*)d_in[23];
  const float* bo_b2 = (const float*)d_in[24];
  const float* w_ih_l0 = (const float*)d_in[25];
  const float* w_hh_l0 = (const float*)d_in[26];
  const float* b_ih_l0 = (const float*)d_in[27];
  const float* b_hh_l0 = (const float*)d_in[28];
  const float* w_ih = (const float*)d_in[29];
  const float* w_hh = (const float*)d_in[30];
  const float* b_ih = (const float*)d_in[31];
  const float* b_hh = (const float*)d_in[32];
  float* outp = (float*)d_out;                     // FP32 output (verified r3)
  unsigned short* ws = (unsigned short*)d_ws;

  // Small buffers at ws front.
  const long o_z     = 0;                        // (2048,16) bf16 for head
  const long o_B2w   = 32768;
  const long o_posew = o_B2w + 24576;
  const long o_B1    = o_posew + 512;
  const long o_bw1   = o_B1 + 36864;
  const long o_bw2   = o_bw1 + 8192;
  const long o_chunk = o_bw2 + 2048;             // = 104960 elements

  // Per-row chunk cost (bf16 elems): pad 2160 + x0 5440 + A 8704 + B 8704 + GI 26112
  const long PERROW = 51120;
  int Bc;
  {
    const size_t margin = 1u << 20;
    size_t need2048 = (size_t)(o_chunk + 2048L * PERROW) * 2 + margin;   // ~210 MB
    size_t need1024 = (size_t)(o_chunk + 1024L * PERROW) * 2 + margin;
    size_t need512  = (size_t)(o_chunk + 512L  * PERROW) * 2 + margin;   // ~53 MB
    if      (ws_size >= need2048) Bc = 2048;
    else if (ws_size >= need1024) Bc = 1024;
    else if (ws_size >= need512)  Bc = 512;
    else                          Bc = 128;
  }
  const int C = 2048 / Bc;
  const long o_pad = o_chunk;
  const long o_x0  = o_pad + (long)Bc * 2160;
  const long o_A   = o_x0  + (long)Bc * 5440;
  const long o_B   = o_A   + (long)Bc * 8704;
  const long o_GI  = o_B   + (long)Bc * 8704;

  k_prep<<<282, 256, 0, stream>>>(squ_w, oenv_w, pose_w, out_w, bo_w1, bo_w2,
                                  ws + o_B2w, ws + o_posew, ws + o_B1, ws + o_bw1, ws + o_bw2);
  k_z<<<8, 256, 0, stream>>>(vid, eps, spk_table, slw, slb, muw, mub, lvw, lvb, outp, ws + o_z);

  for (int c = 0; c < C; ++c){
    long b0 = (long)c * Bc;
    int NG = Bc * 270;
    k_pad<<<NG / 256, 256, 0, stream>>>(beats + b0 * 2040, ws + o_pad, NG);
    k_x0<<<34 * (Bc / 64), 256, 0, stream>>>(ws + o_pad, pre_seq + b0 * 952,
                                             ws + o_B2w, ws + o_posew,
                                             squ_b, oenv_b, pose_b, ws + o_x0);
    // Layer 0: x0 -> A
    k_gi<5, 160><<<Bc / 8, 512, 0, stream>>>(ws + o_x0, ws + o_GI, w_ih_l0, b_ih_l0, 144);
    k_rec<<<Bc / 4, 256, 0, stream>>>(ws + o_GI, ws + o_A, w_hh_l0, b_hh_l0);
    // Layer 1: A -> B
    k_gi<8, 256><<<Bc / 8, 512, 0, stream>>>(ws + o_A, ws + o_GI, w_ih, b_ih, 256);
    k_rec<<<Bc / 4, 256, 0, stream>>>(ws + o_GI, ws + o_B, w_hh, b_hh);
    // Layer 2: B -> A
    k_gi<8, 256><<<Bc / 8, 512, 0, stream>>>(ws + o_B, ws + o_GI,
                                             w_ih + 1L * 2 * 384 * 256, b_ih + 2 * 384, 256);
    k_rec<<<Bc / 4, 256, 0, stream>>>(ws + o_GI, ws + o_A,
                                      w_hh + 1L * 2 * 384 * 128, b_hh + 2 * 384);
    // Layer 3: A -> B
    k_gi<8, 256><<<Bc / 8, 512, 0, stream>>>(ws + o_A, ws + o_GI,
                                             w_ih + 2L * 2 * 384 * 256, b_ih + 4 * 384, 256);
    k_rec<<<Bc / 4, 256, 0, stream>>>(ws + o_GI, ws + o_B,
                                      w_hh + 2L * 2 * 384 * 128, b_hh + 4 * 384);
    k_head<<<Bc * 34 / 128, 512, 0, stream>>>(ws + o_B, ws + o_z,
                                              ws + o_B1, ws + o_bw1, ws + o_bw2,
                                              out_b, bo_b1, bo_b2, outp + b0 * 918);
  }
}

// Round 8
// 512.806 us; speedup vs baseline: 4.0453x; 1.4892x over previous
//
#include <hip/hip_runtime.h>
#include <hip/hip_bf16.h>
#include <stdint.h>

typedef __attribute__((ext_vector_type(8))) short bfrag;   // 8 x bf16 (4 VGPR)
typedef __attribute__((ext_vector_type(4))) float f32x4;   // MFMA acc

__device__ __forceinline__ unsigned short f2bf(float f){
  union { float f; unsigned u; } v; v.f = f;
  unsigned r = v.u + 0x7FFFu + ((v.u >> 16) & 1u);
  return (unsigned short)(r >> 16);
}
__device__ __forceinline__ f32x4 mfma16(bfrag a, bfrag b, f32x4 c){
  return __builtin_amdgcn_mfma_f32_16x16x32_bf16(a, b, c, 0, 0, 0);
}
__device__ __forceinline__ bfrag cvt8(const float* s){
  bfrag r;
  #pragma unroll
  for (int j = 0; j < 8; ++j) r[j] = (short)f2bf(s[j]);
  return r;
}

// ---------------- K0: pad + cast beats chunk (Bc,2,1020)f32 -> (Bc,2,1080)bf16 --
__global__ void k_pad(const float* __restrict__ beats, unsigned short* __restrict__ pad,
                      int NG){
  int g = blockIdx.x * 256 + threadIdx.x;
  if (g >= NG) return;
  int i8 = (g % 135) * 8;
  long rc = g / 135;
  const float* src = beats + rc * 1020;
  union { unsigned short u[8]; bfrag s; } o;
  #pragma unroll
  for (int j = 0; j < 8; ++j){
    int i = i8 + j;
    float v = (i >= 30 && i < 1050) ? src[i - 30] : 0.f;
    o.u[j] = f2bf(v);
  }
  *(bfrag*)(pad + rc * 1080 + i8) = o.s;
}

// ---------------- K1: prep bf16 weight copies (zero-padded at ragged K) --------
__global__ void k_prep(const float* __restrict__ squ_w, const float* __restrict__ oenv_w,
                       const float* __restrict__ pose_w, const float* __restrict__ out_w,
                       const float* __restrict__ bo_w1, const float* __restrict__ bo_w2,
                       unsigned short* __restrict__ B2w, unsigned short* __restrict__ posewp,
                       unsigned short* __restrict__ B1, unsigned short* __restrict__ bow1p,
                       unsigned short* __restrict__ bow2p){
  int i = blockIdx.x * 256 + threadIdx.x;
  if (i < 24576){                                  // B2w: 128 x 192 = [squ|0|oenv|0]
    int o = i / 192, k = i - o * 192;
    float v = 0.f;
    if (k < 90) v = squ_w[o * 90 + k];
    else if (k >= 96 && k < 186) v = oenv_w[o * 90 + (k - 96)];
    B2w[i] = f2bf(v);
    return;
  }
  i -= 24576;
  if (i < 512){                                    // pose_w: 16 x 32
    int o = i / 32, k = i - o * 32;
    posewp[i] = f2bf(k < 28 ? pose_w[o * 28 + k] : 0.f);
    return;
  }
  i -= 512;
  if (i < 36864){                                  // B1: 128 x 288 = [W1|W1|Wz|0]
    int o = i / 288, k = i - o * 288;
    float v = 0.f;
    if (k < 128) v = out_w[o * 144 + k];
    else if (k < 256) v = out_w[o * 144 + (k - 128)];
    else if (k < 272) v = out_w[o * 144 + 128 + (k - 256)];
    B1[i] = f2bf(v);
    return;
  }
  i -= 36864;
  if (i < 8192){ bow1p[i] = f2bf(bo_w1[i]); return; }   // 64 x 128
  i -= 8192;
  if (i < 2048){                                   // bo_w2 padded to 32 x 64
    int o = i / 64, k = i - o * 64;
    bow2p[i] = f2bf(o < 27 ? bo_w2[o * 64 + k] : 0.f);
  }
}

// ---------------- K2: z branch (f32 math, FP32 out), full batch ----------------
__global__ void k_z(const int* __restrict__ vid, const float* __restrict__ eps,
                    const float* __restrict__ spk_table, const float* __restrict__ slw,
                    const float* __restrict__ slb, const float* __restrict__ muw,
                    const float* __restrict__ mub, const float* __restrict__ lvw,
                    const float* __restrict__ lvb,
                    float* __restrict__ outp, unsigned short* __restrict__ zws){
  int b = blockIdx.x * 256 + threadIdx.x;
  if (b >= 2048) return;
  const float* tr = spk_table + (long)vid[b] * 16;
  float t[16], zc0[16];
  #pragma unroll
  for (int k = 0; k < 16; ++k) t[k] = tr[k];
  #pragma unroll
  for (int j = 0; j < 16; ++j){
    float a = slb[j];
    #pragma unroll
    for (int k = 0; k < 16; ++k) a += t[k] * slw[j * 16 + k];
    zc0[j] = a;
  }
  const long ZC = 1880064, ZMU = 1912832, ZLV = 1945600;
  #pragma unroll
  for (int j = 0; j < 16; ++j){
    float mu = mub[j], lv = lvb[j];
    #pragma unroll
    for (int k = 0; k < 16; ++k){ mu += zc0[k] * muw[j * 16 + k]; lv += zc0[k] * lvw[j * 16 + k]; }
    float zc = mu + eps[b * 16 + j] * __expf(0.5f * lv);
    outp[ZMU + b * 16 + j] = mu;
    outp[ZLV + b * 16 + j] = lv;
    outp[ZC + b * 16 + j] = zc;
    zws[b * 16 + j] = f2bf(zc);
  }
}

// ---------------- K3: x0 = [pose | squ+oenv] chunk -> (Bc,34,160) bf16 ---------
__global__ __launch_bounds__(256) void k_x0(
    const unsigned short* __restrict__ pad, const float* __restrict__ pre_seq,
    const unsigned short* __restrict__ B2w, const unsigned short* __restrict__ posewp,
    const float* __restrict__ squ_b, const float* __restrict__ oenv_b,
    const float* __restrict__ pose_b, unsigned short* __restrict__ xbuf0){
  int bid = blockIdx.x;
  int t = bid % 34, bt = bid / 34;
  int w = threadIdx.x >> 6, lane = threadIdx.x & 63;
  int q = lane >> 4, l15 = lane & 15;
  int row = bt * 64 + w * 16 + l15;
  bfrag a[6];
  {
    const unsigned short* p0 = pad + ((long)row * 2) * 1080 + 30 * t;
    #pragma unroll
    for (int kt = 0; kt < 6; ++kt){
      int k = kt * 32 + q * 8;
      const unsigned short* src = (k < 96) ? (p0 + k) : (p0 + 1080 + (k - 96));
      const unsigned int* pu = (const unsigned int*)src;
      union { unsigned int u[4]; bfrag s; } v;
      v.u[0] = pu[0]; v.u[1] = pu[1]; v.u[2] = pu[2]; v.u[3] = pu[3];
      a[kt] = v.s;
    }
  }
  f32x4 acc[8];
  #pragma unroll
  for (int nt = 0; nt < 8; ++nt) acc[nt] = (f32x4){0.f, 0.f, 0.f, 0.f};
  #pragma unroll
  for (int kt = 0; kt < 6; ++kt)
    #pragma unroll
    for (int nt = 0; nt < 8; ++nt){
      bfrag bf = *(const bfrag*)(B2w + ((nt * 16 + l15) * 192 + kt * 32 + q * 8));
      acc[nt] = mfma16(a[kt], bf, acc[nt]);
    }
  f32x4 accp = (f32x4){0.f, 0.f, 0.f, 0.f};
  {
    float av[8];
    const float* ps = pre_seq + ((long)row * 34 + t) * 28;
    if (q < 3){
      #pragma unroll
      for (int j = 0; j < 8; ++j) av[j] = ps[q * 8 + j];
    } else {
      #pragma unroll
      for (int j = 0; j < 4; ++j){ av[j] = ps[24 + j]; av[4 + j] = 0.f; }
    }
    bfrag ap = cvt8(av);
    bfrag bp = *(const bfrag*)(posewp + (l15 * 32 + q * 8));
    accp = mfma16(ap, bp, accp);
  }
  float pb = pose_b[l15];
  int rowc = bt * 64 + w * 16 + q * 4;
  #pragma unroll
  for (int r = 0; r < 4; ++r){
    long base = ((long)(rowc + r) * 34 + t) * 160;
    xbuf0[base + l15] = f2bf(accp[r] + pb);
    xbuf0[base + 144 + l15] = 0;
  }
  #pragma unroll
  for (int nt = 0; nt < 8; ++nt){
    int c = nt * 16 + l15;
    float sb = squ_b[c] + oenv_b[c];
    #pragma unroll
    for (int r = 0; r < 4; ++r){
      long base = ((long)(rowc + r) * 34 + t) * 160;
      xbuf0[base + 16 + c] = f2bf(acc[nt][r] + sb);
    }
  }
}

// ---------------- K4: GRU layer (r4 champion structure). Weights register-
// resident; gi pipelined one step ahead; period-6 static schedule. The ONLY
// change vs the 86-us version: gate divisions -> v_rcp_f32 (raw HW rcp).
// Without this, each 1.f/x compiled to the IEEE div sequence (~10 dependent
// slow ops x 3 per output) which was ~2500 cyc/round — the dominant cost.
#define GRU_STEP(T, S1, S2, PR, HASP, HASGI, HASST) {                            \
    bfrag xreg = (bfrag){0,0,0,0,0,0,0,0};                                       \
    if ((HASST) && xact) xreg = *(const bfrag*)(xin_row + (long)((T)+2) * KI + xv * 8); \
    if (HASP){                                                                   \
      _Pragma("unroll")                                                          \
      for (int r = 0; r < 4; ++r)                                                \
        xout[((long)(rowc + r) * 34 + ((T)-1)) * 256 + d * 128 + col] = hbf[r];  \
    }                                                                            \
    f32x4 gh0 = {0,0,0,0}, gh1 = {0,0,0,0}, gh2 = {0,0,0,0};                     \
    _Pragma("unroll")                                                            \
    for (int kt = 0; kt < 4; ++kt){                                              \
      bfrag ha = *(const bfrag*)(&h_lds[PR][l15 * 136 + kt * 32 + q * 8]);       \
      gh0 = mfma16(ha, bwh[0][kt], gh0);                                         \
      gh1 = mfma16(ha, bwh[1][kt], gh1);                                         \
      gh2 = mfma16(ha, bwh[2][kt], gh2);                                         \
    }                                                                            \
    f32x4 gn0 = {0,0,0,0}, gn1 = {0,0,0,0}, gn2 = {0,0,0,0};                     \
    if (HASGI){                                                                  \
      _Pragma("unroll")                                                          \
      for (int kt = 0; kt < KIT; ++kt){                                          \
        bfrag xa = *(const bfrag*)(&x_lds[S1][l15 * (KI + 8) + kt * 32 + q * 8]);\
        gn0 = mfma16(xa, bgi[0][kt], gn0);                                       \
        gn1 = mfma16(xa, bgi[1][kt], gn1);                                       \
        gn2 = mfma16(xa, bgi[2][kt], gn2);                                       \
      }                                                                          \
    }                                                                            \
    _Pragma("unroll")                                                            \
    for (int r = 0; r < 4; ++r){                                                 \
      float ir = gc0[r] + bi0, iz = gc1[r] + bi1, inn = gc2[r] + bi2;            \
      float hr = gh0[r] + bh0, hz = gh1[r] + bh1, hn = gh2[r] + bh2;             \
      float rg = __builtin_amdgcn_rcpf(1.f + __expf(-(ir + hr)));                \
      float zg = __builtin_amdgcn_rcpf(1.f + __expf(-(iz + hz)));                \
      float pre = inn + rg * hn;                                                 \
      float ax = fabsf(pre);                                                     \
      float th = 1.f - 2.f * __builtin_amdgcn_rcpf(__expf(2.f * ax) + 1.f);      \
      th = (pre < 0.f) ? -th : th;                                               \
      float hv = (1.f - zg) * th + zg * h_old[r];                                \
      h_old[r] = hv;                                                             \
      hbf[r] = f2bf(hv);                                                         \
      h_lds[1 - (PR)][(q * 4 + r) * 136 + col] = hbf[r];                         \
    }                                                                            \
    if (HASGI){ gc0 = gn0; gc1 = gn1; gc2 = gn2; }                               \
    if ((HASST) && xact)                                                         \
      *(bfrag*)(&x_lds[S2][xrow * (KI + 8) + xv * 8]) = xreg;                    \
    __syncthreads();                                                             \
  }

template<int KIT, int KI>
__global__ __launch_bounds__(512, 2) void k_gru(
    const unsigned short* __restrict__ xin, unsigned short* __restrict__ xout,
    const float* __restrict__ wih, const float* __restrict__ whh,
    const float* __restrict__ bih, const float* __restrict__ bhh, int WK){
  __shared__ unsigned short x_lds[3][16 * (KI + 8)];   // x slots t%3
  __shared__ unsigned short h_lds[2][16 * 136];
  int d = blockIdx.x & 1, bt = blockIdx.x >> 1;
  int tid = threadIdx.x;
  int w = tid >> 6, lane = tid & 63, q = lane >> 4, l15 = lane & 15;
  const float* wihd = wih + (long)d * 384 * WK;
  const float* whhd = whh + (long)d * 384 * 128;
  int col = w * 16 + l15;                        // this lane's hidden index
  float bi0 = bih[d * 384 + col], bi1 = bih[d * 384 + 128 + col], bi2 = bih[d * 384 + 256 + col];
  float bh0 = bhh[d * 384 + col], bh1 = bhh[d * 384 + 128 + col], bh2 = bhh[d * 384 + 256 + col];
  // pinned w_ih B-frags (zero-padded past WK)
  bfrag bgi[3][KIT];
  #pragma unroll
  for (int g = 0; g < 3; ++g)
    #pragma unroll
    for (int kt = 0; kt < KIT; ++kt){
      int k = kt * 32 + q * 8;
      if (k < WK){
        float tmp[8];
        const float* s = wihd + (long)(g * 128 + col) * WK + k;
        #pragma unroll
        for (int j = 0; j < 8; ++j) tmp[j] = s[j];
        bgi[g][kt] = cvt8(tmp);
      } else {
        bgi[g][kt] = (bfrag){0, 0, 0, 0, 0, 0, 0, 0};
      }
    }
  // pinned w_hh B-frags (K=128 exact)
  bfrag bwh[3][4];
  #pragma unroll
  for (int g = 0; g < 3; ++g)
    #pragma unroll
    for (int kt = 0; kt < 4; ++kt){
      float tmp[8];
      const float* s = whhd + (long)(g * 128 + col) * 128 + kt * 32 + q * 8;
      #pragma unroll
      for (int j = 0; j < 8; ++j) tmp[j] = s[j];
      bwh[g][kt] = cvt8(tmp);
    }
  const int NV = KI / 8;
  int xrow = tid / NV, xv = tid - xrow * NV;
  bool xact = (tid < 16 * NV);
  const unsigned short* xin_row = xin + ((long)(bt * 16 + (xact ? xrow : 0))) * 34 * KI;
  if (xact){
    *(bfrag*)(&x_lds[0][xrow * (KI + 8) + xv * 8]) = *(const bfrag*)(xin_row + xv * 8);
    *(bfrag*)(&x_lds[1][xrow * (KI + 8) + xv * 8]) = *(const bfrag*)(xin_row + (long)KI + xv * 8);
  }
  for (int i = tid; i < 16 * 136; i += 512) h_lds[0][i] = 0;
  __syncthreads();

  // prologue: gi for t=0 from slot 0
  f32x4 gc0 = {0,0,0,0}, gc1 = {0,0,0,0}, gc2 = {0,0,0,0};
  #pragma unroll
  for (int kt = 0; kt < KIT; ++kt){
    bfrag xa = *(const bfrag*)(&x_lds[0][l15 * (KI + 8) + kt * 32 + q * 8]);
    gc0 = mfma16(xa, bgi[0][kt], gc0);
    gc1 = mfma16(xa, bgi[1][kt], gc1);
    gc2 = mfma16(xa, bgi[2][kt], gc2);
  }
  f32x4 h_old = {0,0,0,0};
  unsigned short hbf[4] = {0, 0, 0, 0};
  int rowc = bt * 16 + q * 4;

  // t: 0..5 peeled, 6..29 in a 6-step loop, 30..33 tail
  GRU_STEP(0, 1, 2, 0, false, true, true)
  GRU_STEP(1, 2, 0, 1, true,  true, true)
  GRU_STEP(2, 0, 1, 0, true,  true, true)
  GRU_STEP(3, 1, 2, 1, true,  true, true)
  GRU_STEP(4, 2, 0, 0, true,  true, true)
  GRU_STEP(5, 0, 1, 1, true,  true, true)
  for (int tt = 6; tt < 30; tt += 6){
    GRU_STEP(tt + 0, 1, 2, 0, true, true, true)
    GRU_STEP(tt + 1, 2, 0, 1, true, true, true)
    GRU_STEP(tt + 2, 0, 1, 0, true, true, true)
    GRU_STEP(tt + 3, 1, 2, 1, true, true, true)
    GRU_STEP(tt + 4, 2, 0, 0, true, true, true)
    GRU_STEP(tt + 5, 0, 1, 1, true, true, true)
  }
  GRU_STEP(30, 1, 2, 0, true, true, true)
  GRU_STEP(31, 2, 0, 1, true, true, true)
  GRU_STEP(32, 0, 1, 0, true, true, false)
  GRU_STEP(33, 1, 2, 1, true, false, false)
  #pragma unroll
  for (int r = 0; r < 4; ++r)
    xout[((long)(rowc + r) * 34 + 33) * 256 + d * 128 + col] = hbf[r];
}

// ---------------- K5: head chunk — feat -> bo1 -> bo2 -> beat (FP32 out) -------
__global__ __launch_bounds__(512) void k_head(
    const unsigned short* __restrict__ xb, const unsigned short* __restrict__ zloc,
    const unsigned short* __restrict__ B1p, const unsigned short* __restrict__ bow1p,
    const unsigned short* __restrict__ bow2p,
    const float* __restrict__ out_b, const float* __restrict__ bo_b1,
    const float* __restrict__ bo_b2, float* __restrict__ outp){
  __shared__ unsigned short B1_lds[128 * 296];
  __shared__ unsigned short feat_lds[128 * 136];
  __shared__ unsigned short bt1_lds[128 * 72];
  int tid = threadIdx.x, w = tid >> 6, lane = tid & 63, q = lane >> 4, l15 = lane & 15;
  long rbase = (long)blockIdx.x * 128;
  for (int v = tid; v < 128 * 36; v += 512){
    int n = v / 36, kc = (v - n * 36) * 8;
    *(bfrag*)(&B1_lds[n * 296 + kc]) = *(const bfrag*)(B1p + n * 288 + kc);
  }
  __syncthreads();
  int rloc = w * 16 + l15;
  long rt = rbase + rloc;
  int bidx = (int)(rt / 34);
  bfrag a1[9];
  #pragma unroll
  for (int kt = 0; kt < 8; ++kt)
    a1[kt] = *(const bfrag*)(xb + rt * 256 + kt * 32 + q * 8);
  if (q < 2) a1[8] = *(const bfrag*)(zloc + (long)bidx * 16 + q * 8);
  else       a1[8] = (bfrag){0, 0, 0, 0, 0, 0, 0, 0};
  f32x4 acc[8];
  #pragma unroll
  for (int nt = 0; nt < 8; ++nt) acc[nt] = (f32x4){0.f, 0.f, 0.f, 0.f};
  #pragma unroll
  for (int kt = 0; kt < 9; ++kt)
    #pragma unroll
    for (int nt = 0; nt < 8; ++nt){
      bfrag b = *(const bfrag*)(&B1_lds[(nt * 16 + l15) * 296 + kt * 32 + q * 8]);
      acc[nt] = mfma16(a1[kt], b, acc[nt]);
    }
  #pragma unroll
  for (int nt = 0; nt < 8; ++nt){
    float bb = out_b[nt * 16 + l15];
    #pragma unroll
    for (int r = 0; r < 4; ++r)
      feat_lds[(w * 16 + q * 4 + r) * 136 + nt * 16 + l15] = f2bf(acc[nt][r] + bb);
  }
  __syncthreads();
  bfrag a2[4];
  #pragma unroll
  for (int kt = 0; kt < 4; ++kt)
    a2[kt] = *(const bfrag*)(&feat_lds[rloc * 136 + kt * 32 + q * 8]);
  f32x4 acc2[4];
  #pragma unroll
  for (int nt = 0; nt < 4; ++nt) acc2[nt] = (f32x4){0.f, 0.f, 0.f, 0.f};
  #pragma unroll
  for (int kt = 0; kt < 4; ++kt)
    #pragma unroll
    for (int nt = 0; nt < 4; ++nt){
      bfrag b = *(const bfrag*)(bow1p + ((nt * 16 + l15) * 128 + kt * 32 + q * 8));
      acc2[nt] = mfma16(a2[kt], b, acc2[nt]);
    }
  #pragma unroll
  for (int nt = 0; nt < 4; ++nt){
    float bb = bo_b1[nt * 16 + l15];
    #pragma unroll
    for (int r = 0; r < 4; ++r)
      bt1_lds[(w * 16 + q * 4 + r) * 72 + nt * 16 + l15] = f2bf(acc2[nt][r] + bb);
  }
  __syncthreads();
  bfrag a3[2];
  #pragma unroll
  for (int kt = 0; kt < 2; ++kt)
    a3[kt] = *(const bfrag*)(&bt1_lds[rloc * 72 + kt * 32 + q * 8]);
  f32x4 acc3[2];
  #pragma unroll
  for (int nt = 0; nt < 2; ++nt) acc3[nt] = (f32x4){0.f, 0.f, 0.f, 0.f};
  #pragma unroll
  for (int kt = 0; kt < 2; ++kt)
    #pragma unroll
    for (int nt = 0; nt < 2; ++nt){
      bfrag b = *(const bfrag*)(bow2p + ((nt * 16 + l15) * 64 + kt * 32 + q * 8));
      acc3[nt] = mfma16(a3[kt], b, acc3[nt]);
    }
  #pragma unroll
  for (int nt = 0; nt < 2; ++nt){
    int n = nt * 16 + l15;
    if (n < 27){
      float bb = bo_b2[n];
      #pragma unroll
      for (int r = 0; r < 4; ++r){
        long rowg = rbase + w * 16 + q * 4 + r;
        outp[rowg * 27 + n] = acc3[nt][r] + bb;
      }
    }
  }
}

extern "C" void kernel_launch(void* const* d_in, const int* in_sizes, int n_in,
                              void* d_out, int out_size, void* d_ws, size_t ws_size,
                              hipStream_t stream){
  (void)in_sizes; (void)n_in; (void)out_size;
  const float* pre_seq = (const float*)d_in[0];
  const float* beats   = (const float*)d_in[1];
  const int*   vid     = (const int*)d_in[4];
  const float* eps     = (const float*)d_in[5];
  const float* spk_table = (const float*)d_in[6];
  const float* slw = (const float*)d_in[7];
  const float* slb = (const float*)d_in[8];
  const float* muw = (const float*)d_in[9];
  const float* mub = (const float*)d_in[10];
  const float* lvw = (const float*)d_in[11];
  const float* lvb = (const float*)d_in[12];
  const float* squ_w = (const float*)d_in[13];
  const float* squ_b = (const float*)d_in[14];
  const float* oenv_w = (const float*)d_in[15];
  const float* oenv_b = (const float*)d_in[16];
  const float* pose_w = (const float*)d_in[17];
  const float* pose_b = (const float*)d_in[18];
  const float* out_w = (const float*)d_in[19];
  const float* out_b = (const float*)d_in[20];
  const float* bo_w1 = (const float*)d_in[21];
  const float* bo_b1 = (const float*)d_in[22];
  const float* bo_w2 = (const float*)d_in[23];
  const float* bo_b2 = (const float*)d_in[24];
  const float* w_ih_l0 = (const float*)d_in[25];
  const float* w_hh_l0 = (const float*)d_in[26];
  const float* b_ih_l0 = (const float*)d_in[27];
  const float* b_hh_l0 = (const float*)d_in[28];
  const float* w_ih = (const float*)d_in[29];
  const float* w_hh = (const float*)d_in[30];
  const float* b_ih = (const float*)d_in[31];
  const float* b_hh = (const float*)d_in[32];
  float* outp = (float*)d_out;                     // FP32 output (verified r3)
  unsigned short* ws = (unsigned short*)d_ws;

  // Small buffers at ws front.
  const long o_z     = 0;                        // (2048,16) bf16 for head
  const long o_B2w   = 32768;
  const long o_posew = o_B2w + 24576;
  const long o_B1    = o_posew + 512;
  const long o_bw1   = o_B1 + 36864;
  const long o_bw2   = o_bw1 + 8192;
  const long o_chunk = o_bw2 + 2048;             // = 104960 elements

  // Footprint-adaptive chunking: per-row cost = pad 2160 + x0 5440 + A 8704 + B 8704
  int Bc;
  {
    const size_t margin = 1u << 20;
    size_t need2048 = (size_t)(o_chunk + 2048L * 25008) * 2 + margin;
    size_t need512  = (size_t)(o_chunk + 512L  * 25008) * 2 + margin;
    if      (ws_size >= need2048) Bc = 2048;
    else if (ws_size >= need512)  Bc = 512;
    else                          Bc = 128;
  }
  const int C = 2048 / Bc;
  const long o_pad = o_chunk;
  const long o_x0  = o_pad + (long)Bc * 2160;
  const long o_A   = o_x0  + (long)Bc * 5440;
  const long o_B   = o_A   + (long)Bc * 8704;

  k_prep<<<282, 256, 0, stream>>>(squ_w, oenv_w, pose_w, out_w, bo_w1, bo_w2,
                                  ws + o_B2w, ws + o_posew, ws + o_B1, ws + o_bw1, ws + o_bw2);
  k_z<<<8, 256, 0, stream>>>(vid, eps, spk_table, slw, slb, muw, mub, lvw, lvb, outp, ws + o_z);

  for (int c = 0; c < C; ++c){
    long b0 = (long)c * Bc;
    int NG = Bc * 270;
    k_pad<<<NG / 256, 256, 0, stream>>>(beats + b0 * 2040, ws + o_pad, NG);
    k_x0<<<34 * (Bc / 64), 256, 0, stream>>>(ws + o_pad, pre_seq + b0 * 952,
                                             ws + o_B2w, ws + o_posew,
                                             squ_b, oenv_b, pose_b, ws + o_x0);
    k_gru<5, 160><<<Bc / 8, 512, 0, stream>>>(ws + o_x0, ws + o_A,
                                              w_ih_l0, w_hh_l0, b_ih_l0, b_hh_l0, 144);
    k_gru<8, 256><<<Bc / 8, 512, 0, stream>>>(ws + o_A, ws + o_B,
                                              w_ih, w_hh, b_ih, b_hh, 256);
    k_gru<8, 256><<<Bc / 8, 512, 0, stream>>>(ws + o_B, ws + o_A,
                                              w_ih + 1L * 2 * 384 * 256, w_hh + 1L * 2 * 384 * 128,
                                              b_ih + 2 * 384, b_hh + 2 * 384, 256);
    k_gru<8, 256><<<Bc / 8, 512, 0, stream>>>(ws + o_A, ws + o_B,
                                              w_ih + 2L * 2 * 384 * 256, w_hh + 2L * 2 * 384 * 128,
                                              b_ih + 4 * 384, b_hh + 4 * 384, 256);
    k_head<<<Bc * 34 / 128, 512, 0, stream>>>(ws + o_B, ws + o_z,
                                              ws + o_B1, ws + o_bw1, ws + o_bw2,
                                              out_b, bo_b1, bo_b2, outp + b0 * 918);
  }
}

// Round 9
// 460.812 us; speedup vs baseline: 4.5017x; 1.1128x over previous
//
#include <hip/hip_runtime.h>
#include <hip/hip_bf16.h>
#include <stdint.h>

typedef __attribute__((ext_vector_type(8))) short bfrag;   // 8 x bf16 (4 VGPR)
typedef __attribute__((ext_vector_type(4))) float f32x4;   // MFMA acc

__device__ __forceinline__ unsigned short f2bf(float f){
  union { float f; unsigned u; } v; v.f = f;
  unsigned r = v.u + 0x7FFFu + ((v.u >> 16) & 1u);
  return (unsigned short)(r >> 16);
}
__device__ __forceinline__ f32x4 mfma16(bfrag a, bfrag b, f32x4 c){
  return __builtin_amdgcn_mfma_f32_16x16x32_bf16(a, b, c, 0, 0, 0);
}
__device__ __forceinline__ bfrag cvt8(const float* s){
  bfrag r;
  #pragma unroll
  for (int j = 0; j < 8; ++j) r[j] = (short)f2bf(s[j]);
  return r;
}
// Barrier with LDS-only drain: cross-wave data in this kernel is LDS only, so
// waiting lgkmcnt(0) before s_barrier is sufficient; skipping the vmcnt(0)
// drain keeps xout stores and x prefetch loads in flight across rounds.
__device__ __forceinline__ void lds_barrier(){
  __asm__ volatile("s_waitcnt lgkmcnt(0)\n\ts_barrier" ::: "memory");
}

// ---------------- K0: pad + cast beats chunk (Bc,2,1020)f32 -> (Bc,2,1080)bf16 --
__global__ void k_pad(const float* __restrict__ beats, unsigned short* __restrict__ pad,
                      int NG){
  int g = blockIdx.x * 256 + threadIdx.x;
  if (g >= NG) return;
  int i8 = (g % 135) * 8;
  long rc = g / 135;
  const float* src = beats + rc * 1020;
  union { unsigned short u[8]; bfrag s; } o;
  #pragma unroll
  for (int j = 0; j < 8; ++j){
    int i = i8 + j;
    float v = (i >= 30 && i < 1050) ? src[i - 30] : 0.f;
    o.u[j] = f2bf(v);
  }
  *(bfrag*)(pad + rc * 1080 + i8) = o.s;
}

// ---------------- K1: prep bf16 weight copies (zero-padded at ragged K) --------
__global__ void k_prep(const float* __restrict__ squ_w, const float* __restrict__ oenv_w,
                       const float* __restrict__ pose_w, const float* __restrict__ out_w,
                       const float* __restrict__ bo_w1, const float* __restrict__ bo_w2,
                       unsigned short* __restrict__ B2w, unsigned short* __restrict__ posewp,
                       unsigned short* __restrict__ B1, unsigned short* __restrict__ bow1p,
                       unsigned short* __restrict__ bow2p){
  int i = blockIdx.x * 256 + threadIdx.x;
  if (i < 24576){                                  // B2w: 128 x 192 = [squ|0|oenv|0]
    int o = i / 192, k = i - o * 192;
    float v = 0.f;
    if (k < 90) v = squ_w[o * 90 + k];
    else if (k >= 96 && k < 186) v = oenv_w[o * 90 + (k - 96)];
    B2w[i] = f2bf(v);
    return;
  }
  i -= 24576;
  if (i < 512){                                    // pose_w: 16 x 32
    int o = i / 32, k = i - o * 32;
    posewp[i] = f2bf(k < 28 ? pose_w[o * 28 + k] : 0.f);
    return;
  }
  i -= 512;
  if (i < 36864){                                  // B1: 128 x 288 = [W1|W1|Wz|0]
    int o = i / 288, k = i - o * 288;
    float v = 0.f;
    if (k < 128) v = out_w[o * 144 + k];
    else if (k < 256) v = out_w[o * 144 + (k - 128)];
    else if (k < 272) v = out_w[o * 144 + 128 + (k - 256)];
    B1[i] = f2bf(v);
    return;
  }
  i -= 36864;
  if (i < 8192){ bow1p[i] = f2bf(bo_w1[i]); return; }   // 64 x 128
  i -= 8192;
  if (i < 2048){                                   // bo_w2 padded to 32 x 64
    int o = i / 64, k = i - o * 64;
    bow2p[i] = f2bf(o < 27 ? bo_w2[o * 64 + k] : 0.f);
  }
}

// ---------------- K2: z branch (f32 math, FP32 out), full batch ----------------
__global__ void k_z(const int* __restrict__ vid, const float* __restrict__ eps,
                    const float* __restrict__ spk_table, const float* __restrict__ slw,
                    const float* __restrict__ slb, const float* __restrict__ muw,
                    const float* __restrict__ mub, const float* __restrict__ lvw,
                    const float* __restrict__ lvb,
                    float* __restrict__ outp, unsigned short* __restrict__ zws){
  int b = blockIdx.x * 256 + threadIdx.x;
  if (b >= 2048) return;
  const float* tr = spk_table + (long)vid[b] * 16;
  float t[16], zc0[16];
  #pragma unroll
  for (int k = 0; k < 16; ++k) t[k] = tr[k];
  #pragma unroll
  for (int j = 0; j < 16; ++j){
    float a = slb[j];
    #pragma unroll
    for (int k = 0; k < 16; ++k) a += t[k] * slw[j * 16 + k];
    zc0[j] = a;
  }
  const long ZC = 1880064, ZMU = 1912832, ZLV = 1945600;
  #pragma unroll
  for (int j = 0; j < 16; ++j){
    float mu = mub[j], lv = lvb[j];
    #pragma unroll
    for (int k = 0; k < 16; ++k){ mu += zc0[k] * muw[j * 16 + k]; lv += zc0[k] * lvw[j * 16 + k]; }
    float zc = mu + eps[b * 16 + j] * __expf(0.5f * lv);
    outp[ZMU + b * 16 + j] = mu;
    outp[ZLV + b * 16 + j] = lv;
    outp[ZC + b * 16 + j] = zc;
    zws[b * 16 + j] = f2bf(zc);
  }
}

// ---------------- K3: x0 = [pose | squ+oenv] chunk -> (Bc,34,160) bf16 ---------
__global__ __launch_bounds__(256) void k_x0(
    const unsigned short* __restrict__ pad, const float* __restrict__ pre_seq,
    const unsigned short* __restrict__ B2w, const unsigned short* __restrict__ posewp,
    const float* __restrict__ squ_b, const float* __restrict__ oenv_b,
    const float* __restrict__ pose_b, unsigned short* __restrict__ xbuf0){
  int bid = blockIdx.x;
  int t = bid % 34, bt = bid / 34;
  int w = threadIdx.x >> 6, lane = threadIdx.x & 63;
  int q = lane >> 4, l15 = lane & 15;
  int row = bt * 64 + w * 16 + l15;
  bfrag a[6];
  {
    const unsigned short* p0 = pad + ((long)row * 2) * 1080 + 30 * t;
    #pragma unroll
    for (int kt = 0; kt < 6; ++kt){
      int k = kt * 32 + q * 8;
      const unsigned short* src = (k < 96) ? (p0 + k) : (p0 + 1080 + (k - 96));
      const unsigned int* pu = (const unsigned int*)src;
      union { unsigned int u[4]; bfrag s; } v;
      v.u[0] = pu[0]; v.u[1] = pu[1]; v.u[2] = pu[2]; v.u[3] = pu[3];
      a[kt] = v.s;
    }
  }
  f32x4 acc[8];
  #pragma unroll
  for (int nt = 0; nt < 8; ++nt) acc[nt] = (f32x4){0.f, 0.f, 0.f, 0.f};
  #pragma unroll
  for (int kt = 0; kt < 6; ++kt)
    #pragma unroll
    for (int nt = 0; nt < 8; ++nt){
      bfrag bf = *(const bfrag*)(B2w + ((nt * 16 + l15) * 192 + kt * 32 + q * 8));
      acc[nt] = mfma16(a[kt], bf, acc[nt]);
    }
  f32x4 accp = (f32x4){0.f, 0.f, 0.f, 0.f};
  {
    float av[8];
    const float* ps = pre_seq + ((long)row * 34 + t) * 28;
    if (q < 3){
      #pragma unroll
      for (int j = 0; j < 8; ++j) av[j] = ps[q * 8 + j];
    } else {
      #pragma unroll
      for (int j = 0; j < 4; ++j){ av[j] = ps[24 + j]; av[4 + j] = 0.f; }
    }
    bfrag ap = cvt8(av);
    bfrag bp = *(const bfrag*)(posewp + (l15 * 32 + q * 8));
    accp = mfma16(ap, bp, accp);
  }
  float pb = pose_b[l15];
  int rowc = bt * 64 + w * 16 + q * 4;
  #pragma unroll
  for (int r = 0; r < 4; ++r){
    long base = ((long)(rowc + r) * 34 + t) * 160;
    xbuf0[base + l15] = f2bf(accp[r] + pb);
    xbuf0[base + 144 + l15] = 0;
  }
  #pragma unroll
  for (int nt = 0; nt < 8; ++nt){
    int c = nt * 16 + l15;
    float sb = squ_b[c] + oenv_b[c];
    #pragma unroll
    for (int r = 0; r < 4; ++r){
      long base = ((long)(rowc + r) * 34 + t) * 160;
      xbuf0[base + 16 + c] = f2bf(acc[nt][r] + sb);
    }
  }
}

// ---------------- K4: GRU layer. Weights register-resident; gi pipelined one
// step ahead; LDS-only barrier (no vmcnt drain); x prefetched with ~2 rounds of
// slack: load x[T+3] at top of step T, ds_write it at bottom of step T+1.
#define GRU_STEP(T, S1, S2, PR, HASP, HASGI, HASLD, HASST) {                     \
    if ((HASLD) && xact)                                                         \
      pf_new = *(const bfrag*)(xin_row + (long)((T)+3) * KI + xv * 8);           \
    if (HASP){                                                                   \
      _Pragma("unroll")                                                          \
      for (int r = 0; r < 4; ++r)                                                \
        xout[((long)(rowc + r) * 34 + ((T)-1)) * 256 + d * 128 + col] = hbf[r];  \
    }                                                                            \
    f32x4 gh0 = {0,0,0,0}, gh1 = {0,0,0,0}, gh2 = {0,0,0,0};                     \
    _Pragma("unroll")                                                            \
    for (int kt = 0; kt < 4; ++kt){                                              \
      bfrag ha = *(const bfrag*)(&h_lds[PR][l15 * 136 + kt * 32 + q * 8]);       \
      gh0 = mfma16(ha, bwh[0][kt], gh0);                                         \
      gh1 = mfma16(ha, bwh[1][kt], gh1);                                         \
      gh2 = mfma16(ha, bwh[2][kt], gh2);                                         \
    }                                                                            \
    f32x4 gn0 = {0,0,0,0}, gn1 = {0,0,0,0}, gn2 = {0,0,0,0};                     \
    if (HASGI){                                                                  \
      _Pragma("unroll")                                                          \
      for (int kt = 0; kt < KIT; ++kt){                                          \
        bfrag xa = *(const bfrag*)(&x_lds[S1][l15 * (KI + 8) + kt * 32 + q * 8]);\
        gn0 = mfma16(xa, bgi[0][kt], gn0);                                       \
        gn1 = mfma16(xa, bgi[1][kt], gn1);                                       \
        gn2 = mfma16(xa, bgi[2][kt], gn2);                                       \
      }                                                                          \
    }                                                                            \
    _Pragma("unroll")                                                            \
    for (int r = 0; r < 4; ++r){                                                 \
      float ir = gc0[r] + bi0, iz = gc1[r] + bi1, inn = gc2[r] + bi2;            \
      float hr = gh0[r] + bh0, hz = gh1[r] + bh1, hn = gh2[r] + bh2;             \
      float rg = __builtin_amdgcn_rcpf(1.f + __expf(-(ir + hr)));                \
      float zg = __builtin_amdgcn_rcpf(1.f + __expf(-(iz + hz)));                \
      float pre = inn + rg * hn;                                                 \
      float ax = fabsf(pre);                                                     \
      float th = 1.f - 2.f * __builtin_amdgcn_rcpf(__expf(2.f * ax) + 1.f);      \
      th = (pre < 0.f) ? -th : th;                                               \
      float hv = (1.f - zg) * th + zg * h_old[r];                                \
      h_old[r] = hv;                                                             \
      hbf[r] = f2bf(hv);                                                         \
      h_lds[1 - (PR)][(q * 4 + r) * 136 + col] = hbf[r];                         \
    }                                                                            \
    if (HASGI){ gc0 = gn0; gc1 = gn1; gc2 = gn2; }                               \
    if ((HASST) && xact){                                                        \
      *(bfrag*)(&x_lds[S2][xrow * (KI + 8) + xv * 8]) = pf_hold;                 \
      pf_hold = pf_new;                                                          \
    }                                                                            \
    lds_barrier();                                                               \
  }

template<int KIT, int KI>
__global__ __launch_bounds__(512, 2) void k_gru(
    const unsigned short* __restrict__ xin, unsigned short* __restrict__ xout,
    const float* __restrict__ wih, const float* __restrict__ whh,
    const float* __restrict__ bih, const float* __restrict__ bhh, int WK){
  __shared__ unsigned short x_lds[3][16 * (KI + 8)];   // x slots t%3
  __shared__ unsigned short h_lds[2][16 * 136];
  int d = blockIdx.x & 1, bt = blockIdx.x >> 1;
  int tid = threadIdx.x;
  int w = tid >> 6, lane = tid & 63, q = lane >> 4, l15 = lane & 15;
  const float* wihd = wih + (long)d * 384 * WK;
  const float* whhd = whh + (long)d * 384 * 128;
  int col = w * 16 + l15;                        // this lane's hidden index
  float bi0 = bih[d * 384 + col], bi1 = bih[d * 384 + 128 + col], bi2 = bih[d * 384 + 256 + col];
  float bh0 = bhh[d * 384 + col], bh1 = bhh[d * 384 + 128 + col], bh2 = bhh[d * 384 + 256 + col];
  // pinned w_ih B-frags (zero-padded past WK)
  bfrag bgi[3][KIT];
  #pragma unroll
  for (int g = 0; g < 3; ++g)
    #pragma unroll
    for (int kt = 0; kt < KIT; ++kt){
      int k = kt * 32 + q * 8;
      if (k < WK){
        float tmp[8];
        const float* s = wihd + (long)(g * 128 + col) * WK + k;
        #pragma unroll
        for (int j = 0; j < 8; ++j) tmp[j] = s[j];
        bgi[g][kt] = cvt8(tmp);
      } else {
        bgi[g][kt] = (bfrag){0, 0, 0, 0, 0, 0, 0, 0};
      }
    }
  // pinned w_hh B-frags (K=128 exact)
  bfrag bwh[3][4];
  #pragma unroll
  for (int g = 0; g < 3; ++g)
    #pragma unroll
    for (int kt = 0; kt < 4; ++kt){
      float tmp[8];
      const float* s = whhd + (long)(g * 128 + col) * 128 + kt * 32 + q * 8;
      #pragma unroll
      for (int j = 0; j < 8; ++j) tmp[j] = s[j];
      bwh[g][kt] = cvt8(tmp);
    }
  const int NV = KI / 8;
  int xrow = tid / NV, xv = tid - xrow * NV;
  bool xact = (tid < 16 * NV);
  const unsigned short* xin_row = xin + ((long)(bt * 16 + (xact ? xrow : 0))) * 34 * KI;
  bfrag pf_hold = (bfrag){0,0,0,0,0,0,0,0}, pf_new = (bfrag){0,0,0,0,0,0,0,0};
  if (xact){
    *(bfrag*)(&x_lds[0][xrow * (KI + 8) + xv * 8]) = *(const bfrag*)(xin_row + xv * 8);
    *(bfrag*)(&x_lds[1][xrow * (KI + 8) + xv * 8]) = *(const bfrag*)(xin_row + (long)KI + xv * 8);
    pf_hold = *(const bfrag*)(xin_row + 2L * KI + xv * 8);   // x[2], written at step 0
  }
  for (int i = tid; i < 16 * 136; i += 512) h_lds[0][i] = 0;
  __syncthreads();

  // prologue: gi for t=0 from slot 0
  f32x4 gc0 = {0,0,0,0}, gc1 = {0,0,0,0}, gc2 = {0,0,0,0};
  #pragma unroll
  for (int kt = 0; kt < KIT; ++kt){
    bfrag xa = *(const bfrag*)(&x_lds[0][l15 * (KI + 8) + kt * 32 + q * 8]);
    gc0 = mfma16(xa, bgi[0][kt], gc0);
    gc1 = mfma16(xa, bgi[1][kt], gc1);
    gc2 = mfma16(xa, bgi[2][kt], gc2);
  }
  f32x4 h_old = {0,0,0,0};
  unsigned short hbf[4] = {0, 0, 0, 0};
  int rowc = bt * 16 + q * 4;

  // t: 0..5 peeled, 6..29 in a 6-step loop, 30..33 tail
  // HASLD: T<=30 (loads x[T+3]); HASST: T<=31 (writes x[T+2] = pf_hold)
  GRU_STEP(0, 1, 2, 0, false, true, true, true)
  GRU_STEP(1, 2, 0, 1, true,  true, true, true)
  GRU_STEP(2, 0, 1, 0, true,  true, true, true)
  GRU_STEP(3, 1, 2, 1, true,  true, true, true)
  GRU_STEP(4, 2, 0, 0, true,  true, true, true)
  GRU_STEP(5, 0, 1, 1, true,  true, true, true)
  for (int tt = 6; tt < 30; tt += 6){
    GRU_STEP(tt + 0, 1, 2, 0, true, true, (tt + 0 <= 30), true)
    GRU_STEP(tt + 1, 2, 0, 1, true, true, (tt + 1 <= 30), true)
    GRU_STEP(tt + 2, 0, 1, 0, true, true, (tt + 2 <= 30), true)
    GRU_STEP(tt + 3, 1, 2, 1, true, true, (tt + 3 <= 30), true)
    GRU_STEP(tt + 4, 2, 0, 0, true, true, (tt + 4 <= 30), true)
    GRU_STEP(tt + 5, 0, 1, 1, true, true, (tt + 5 <= 30), true)
  }
  GRU_STEP(30, 1, 2, 0, true, true, true,  true)
  GRU_STEP(31, 2, 0, 1, true, true, false, true)
  GRU_STEP(32, 0, 1, 0, true, true, false, false)
  GRU_STEP(33, 1, 2, 1, true, false, false, false)
  #pragma unroll
  for (int r = 0; r < 4; ++r)
    xout[((long)(rowc + r) * 34 + 33) * 256 + d * 128 + col] = hbf[r];
}

// ---------------- K5: head chunk — feat -> bo1 -> bo2 -> beat (FP32 out) -------
__global__ __launch_bounds__(512) void k_head(
    const unsigned short* __restrict__ xb, const unsigned short* __restrict__ zloc,
    const unsigned short* __restrict__ B1p, const unsigned short* __restrict__ bow1p,
    const unsigned short* __restrict__ bow2p,
    const float* __restrict__ out_b, const float* __restrict__ bo_b1,
    const float* __restrict__ bo_b2, float* __restrict__ outp){
  __shared__ unsigned short B1_lds[128 * 296];
  __shared__ unsigned short feat_lds[128 * 136];
  __shared__ unsigned short bt1_lds[128 * 72];
  int tid = threadIdx.x, w = tid >> 6, lane = tid & 63, q = lane >> 4, l15 = lane & 15;
  long rbase = (long)blockIdx.x * 128;
  for (int v = tid; v < 128 * 36; v += 512){
    int n = v / 36, kc = (v - n * 36) * 8;
    *(bfrag*)(&B1_lds[n * 296 + kc]) = *(const bfrag*)(B1p + n * 288 + kc);
  }
  __syncthreads();
  int rloc = w * 16 + l15;
  long rt = rbase + rloc;
  int bidx = (int)(rt / 34);
  bfrag a1[9];
  #pragma unroll
  for (int kt = 0; kt < 8; ++kt)
    a1[kt] = *(const bfrag*)(xb + rt * 256 + kt * 32 + q * 8);
  if (q < 2) a1[8] = *(const bfrag*)(zloc + (long)bidx * 16 + q * 8);
  else       a1[8] = (bfrag){0, 0, 0, 0, 0, 0, 0, 0};
  f32x4 acc[8];
  #pragma unroll
  for (int nt = 0; nt < 8; ++nt) acc[nt] = (f32x4){0.f, 0.f, 0.f, 0.f};
  #pragma unroll
  for (int kt = 0; kt < 9; ++kt)
    #pragma unroll
    for (int nt = 0; nt < 8; ++nt){
      bfrag b = *(const bfrag*)(&B1_lds[(nt * 16 + l15) * 296 + kt * 32 + q * 8]);
      acc[nt] = mfma16(a1[kt], b, acc[nt]);
    }
  #pragma unroll
  for (int nt = 0; nt < 8; ++nt){
    float bb = out_b[nt * 16 + l15];
    #pragma unroll
    for (int r = 0; r < 4; ++r)
      feat_lds[(w * 16 + q * 4 + r) * 136 + nt * 16 + l15] = f2bf(acc[nt][r] + bb);
  }
  __syncthreads();
  bfrag a2[4];
  #pragma unroll
  for (int kt = 0; kt < 4; ++kt)
    a2[kt] = *(const bfrag*)(&feat_lds[rloc * 136 + kt * 32 + q * 8]);
  f32x4 acc2[4];
  #pragma unroll
  for (int nt = 0; nt < 4; ++nt) acc2[nt] = (f32x4){0.f, 0.f, 0.f, 0.f};
  #pragma unroll
  for (int kt = 0; kt < 4; ++kt)
    #pragma unroll
    for (int nt = 0; nt < 4; ++nt){
      bfrag b = *(const bfrag*)(bow1p + ((nt * 16 + l15) * 128 + kt * 32 + q * 8));
      acc2[nt] = mfma16(a2[kt], b, acc2[nt]);
    }
  #pragma unroll
  for (int nt = 0; nt < 4; ++nt){
    float bb = bo_b1[nt * 16 + l15];
    #pragma unroll
    for (int r = 0; r < 4; ++r)
      bt1_lds[(w * 16 + q * 4 + r) * 72 + nt * 16 + l15] = f2bf(acc2[nt][r] + bb);
  }
  __syncthreads();
  bfrag a3[2];
  #pragma unroll
  for (int kt = 0; kt < 2; ++kt)
    a3[kt] = *(const bfrag*)(&bt1_lds[rloc * 72 + kt * 32 + q * 8]);
  f32x4 acc3[2];
  #pragma unroll
  for (int nt = 0; nt < 2; ++nt) acc3[nt] = (f32x4){0.f, 0.f, 0.f, 0.f};
  #pragma unroll
  for (int kt = 0; kt < 2; ++kt)
    #pragma unroll
    for (int nt = 0; nt < 2; ++nt){
      bfrag b = *(const bfrag*)(bow2p + ((nt * 16 + l15) * 64 + kt * 32 + q * 8));
      acc3[nt] = mfma16(a3[kt], b, acc3[nt]);
    }
  #pragma unroll
  for (int nt = 0; nt < 2; ++nt){
    int n = nt * 16 + l15;
    if (n < 27){
      float bb = bo_b2[n];
      #pragma unroll
      for (int r = 0; r < 4; ++r){
        long rowg = rbase + w * 16 + q * 4 + r;
        outp[rowg * 27 + n] = acc3[nt][r] + bb;
      }
    }
  }
}

extern "C" void kernel_launch(void* const* d_in, const int* in_sizes, int n_in,
                              void* d_out, int out_size, void* d_ws, size_t ws_size,
                              hipStream_t stream){
  (void)in_sizes; (void)n_in; (void)out_size;
  const float* pre_seq = (const float*)d_in[0];
  const float* beats   = (const float*)d_in[1];
  const int*   vid     = (const int*)d_in[4];
  const float* eps     = (const float*)d_in[5];
  const float* spk_table = (const float*)d_in[6];
  const float* slw = (const float*)d_in[7];
  const float* slb = (const float*)d_in[8];
  const float* muw = (const float*)d_in[9];
  const float* mub = (const float*)d_in[10];
  const float* lvw = (const float*)d_in[11];
  const float* lvb = (const float*)d_in[12];
  const float* squ_w = (const float*)d_in[13];
  const float* squ_b = (const float*)d_in[14];
  const float* oenv_w = (const float*)d_in[15];
  const float* oenv_b = (const float*)d_in[16];
  const float* pose_w = (const float*)d_in[17];
  const float* pose_b = (const float*)d_in[18];
  const float* out_w = (const float*)d_in[19];
  const float* out_b = (const float*)d_in[20];
  const float* bo_w1 = (const float*)d_in[21];
  const float* bo_b1 = (const float*)d_in[22];
  const float* bo_w2 = (const float*)d_in[23];
  const float* bo_b2 = (const float*)d_in[24];
  const float* w_ih_l0 = (const float*)d_in[25];
  const float* w_hh_l0 = (const float*)d_in[26];
  const float* b_ih_l0 = (const float*)d_in[27];
  const float* b_hh_l0 = (const float*)d_in[28];
  const float* w_ih = (const float*)d_in[29];
  const float* w_hh = (const float*)d_in[30];
  const float* b_ih = (const float*)d_in[31];
  const float* b_hh = (const float*)d_in[32];
  float* outp = (float*)d_out;                     // FP32 output (verified r3)
  unsigned short* ws = (unsigned short*)d_ws;

  // Small buffers at ws front.
  const long o_z     = 0;                        // (2048,16) bf16 for head
  const long o_B2w   = 32768;
  const long o_posew = o_B2w + 24576;
  const long o_B1    = o_posew + 512;
  const long o_bw1   = o_B1 + 36864;
  const long o_bw2   = o_bw1 + 8192;
  const long o_chunk = o_bw2 + 2048;             // = 104960 elements

  // Footprint-adaptive chunking: per-row cost = pad 2160 + x0 5440 + A 8704 + B 8704
  int Bc;
  {
    const size_t margin = 1u << 20;
    size_t need2048 = (size_t)(o_chunk + 2048L * 25008) * 2 + margin;
    size_t need512  = (size_t)(o_chunk + 512L  * 25008) * 2 + margin;
    if      (ws_size >= need2048) Bc = 2048;
    else if (ws_size >= need512)  Bc = 512;
    else                          Bc = 128;
  }
  const int C = 2048 / Bc;
  const long o_pad = o_chunk;
  const long o_x0  = o_pad + (long)Bc * 2160;
  const long o_A   = o_x0  + (long)Bc * 5440;
  const long o_B   = o_A   + (long)Bc * 8704;

  k_prep<<<282, 256, 0, stream>>>(squ_w, oenv_w, pose_w, out_w, bo_w1, bo_w2,
                                  ws + o_B2w, ws + o_posew, ws + o_B1, ws + o_bw1, ws + o_bw2);
  k_z<<<8, 256, 0, stream>>>(vid, eps, spk_table, slw, slb, muw, mub, lvw, lvb, outp, ws + o_z);

  for (int c = 0; c < C; ++c){
    long b0 = (long)c * Bc;
    int NG = Bc * 270;
    k_pad<<<NG / 256, 256, 0, stream>>>(beats + b0 * 2040, ws + o_pad, NG);
    k_x0<<<34 * (Bc / 64), 256, 0, stream>>>(ws + o_pad, pre_seq + b0 * 952,
                                             ws + o_B2w, ws + o_posew,
                                             squ_b, oenv_b, pose_b, ws + o_x0);
    k_gru<5, 160><<<Bc / 8, 512, 0, stream>>>(ws + o_x0, ws + o_A,
                                              w_ih_l0, w_hh_l0, b_ih_l0, b_hh_l0, 144);
    k_gru<8, 256><<<Bc / 8, 512, 0, stream>>>(ws + o_A, ws + o_B,
                                              w_ih, w_hh, b_ih, b_hh, 256);
    k_gru<8, 256><<<Bc / 8, 512, 0, stream>>>(ws + o_B, ws + o_A,
                                              w_ih + 1L * 2 * 384 * 256, w_hh + 1L * 2 * 384 * 128,
                                              b_ih + 2 * 384, b_hh + 2 * 384, 256);
    k_gru<8, 256><<<Bc / 8, 512, 0, stream>>>(ws + o_A, ws + o_B,
                                              w_ih + 2L * 2 * 384 * 256, w_hh + 2L * 2 * 384 * 128,
                                              b_ih + 4 * 384, b_hh + 4 * 384, 256);
    k_head<<<Bc * 34 / 128, 512, 0, stream>>>(ws + o_B, ws + o_z,
                                              ws + o_B1, ws + o_bw1, ws + o_bw2,
                                              out_b, bo_b1, bo_b2, outp + b0 * 918);
  }
}